// Round 15
// baseline (1569.445 us; speedup 1.0000x reference)
//
#include <hip/hip_runtime.h>
#include <hip/hip_bf16.h>
#include <stdint.h>

#define HD   512   // hidden dim H
#define ID   128   // input dim I
#define NCLS 100   // num classes
#define TT   512   // sequence length T
#define BB   128   // batch B
#define NEMB 101   // NC + 1 embedding rows
#define THR  512   // threads per recurrence WG (8 waves, 2 waves/SIMD)

// f32 geometry: 32 groups x 8 WGs x 64 cols, 4 rows/group.
#define NGRPF 32
#define GWGF  8
#define RPGF  4
#define COLSF 64
// bf16 geometry: 64 groups x 4 WGs x 128 cols, 2 rows/group.
#define NGRPB 64
#define GWGB  4
#define RPGB  2
#define COLSB 128

#define CPAD 640   // f32 LDS C row stride (32 chunks x (16 data + 4 pad))
#define CBW  260   // packed-bf16 C row stride in u32 (256 pairs + 4 pad)
#define PROW 2056  // f32 partials row stride in float2 (2048 slots + 8 pad)
#define PSTB 3     // bf16-path partials stride in float2

// workspace layout (bytes)
#define WS_FLAG 0
#define WS_BAR  4096                   // u32 bars[NGRP*32] (startup barrier)
#define WS_G    65536                  // float G[101][2048]  (808 KB)
#define WS_C0   (1u * 1024 * 1024)     // C0: tagged u32 exchange buffer
#define WS_C1   (WS_C0 + 262144)
#define WS_HFB  (WS_C1 + 262144)       // float Hfb[128][512] (256 KB)
#define NBARU   4096
#define NCU     65536                  // u32s per C buffer

using bf16 = __hip_bfloat16;

__device__ __forceinline__ float b2f(bf16 v) { return __bfloat162float(v); }
__device__ __forceinline__ float sigf(float x) { return 1.0f / (1.0f + expf(-x)); }

// Agent-scope accessors — proven (die-level coherence point).
// LEDGER:
//  r1: separate flag+data exchange — lost to central RMW.
//  r3/r4: sc0 same-XCD L2 transport — stale L1; refuted. Do not retry.
//  r5: ext_vector v2f — hipcc scalarizes.
//  r6-r8 "nulls" VOID: flag=0 (inputs f32); bf16-path edits were dead.
//  r9: tagged dataflow (2-bit step tag in mantissa) — WIN 1469->1375.
//  r10: wave-local stage + narrow poll — NULL (1379).
//  r11: forced v_pk_fma_f32 — NULL: compute off the critical chain.
//  r12: [col][4row] repack — REGRESSION: broke publish coalescing (4x WRITE).
//  r13: single barrier/step + [row][slot] partials — WIN: recur 1334 (best).
//  r14: dispatch merge (runtime branch) — total 1580->1420 BUT recur
//      1334->1401: merged-branch codegen tax (co-compiled bodies perturb
//      the hot loop's scheduling/regalloc).
//  r15 (this round): HOST-SIDE dtype discrimination via in_sizes[3]
//      (Wfc bytes: HD*HD*4 -> f32, HD*HD*2 -> bf16, else -> r13 dual
//      fallback). Restores r13's standalone-template codegen (1334) AND
//      r14's 4-dispatch count. Device code = r13 verbatim.
__device__ __forceinline__ float cld(const float* p) {
    return __hip_atomic_load(p, __ATOMIC_RELAXED, __HIP_MEMORY_SCOPE_AGENT);
}
__device__ __forceinline__ void cst(float* p, float v) {
    __hip_atomic_store(p, v, __ATOMIC_RELAXED, __HIP_MEMORY_SCOPE_AGENT);
}
__device__ __forceinline__ void cstu(uint32_t* p, uint32_t v) {
    __hip_atomic_store(p, v, __ATOMIC_RELAXED, __HIP_MEMORY_SCOPE_AGENT);
}
__device__ __forceinline__ uint32_t cldu(const uint32_t* p) {
    return __hip_atomic_load(p, __ATOMIC_RELAXED, __HIP_MEMORY_SCOPE_AGENT);
}
__device__ __forceinline__ uint64_t cldu8(const uint64_t* p) {
    return __hip_atomic_load(p, __ATOMIC_RELAXED, __HIP_MEMORY_SCOPE_AGENT);
}

// pack two f32 into bf16x2 (low = first arg) — gfx950-verified instruction
__device__ __forceinline__ uint32_t pkbf(float x, float y) {
    uint32_t u;
    asm("v_cvt_pk_bf16_f32 %0, %1, %2" : "=v"(u) : "v"(x), "v"(y));
    return u;
}
// 2-way bf16 dot with f32 accumulate (VOP3P) — schedulable.
#define DOT2(acc, w, c) \
    asm("v_dot2_f32_bf16 %0, %1, %2, %0" : "+v"(acc) : "v"(w), "v"(c))

template <bool BF>
__device__ __forceinline__ float ldv(const void* p, int i) {
    if constexpr (BF) return b2f(((const bf16*)p)[i]);
    else              return ((const float*)p)[i];
}

// padded f32 Cs index for h' (16 data floats + 4 pad per chunk)
__device__ __forceinline__ int cpi(int h) { return (h >> 4) * 20 + (h & 15); }

// ---------------------------------------------------------------------------
// Group barrier — STARTUP-ONLY (per-step barriers deleted since r9).
// ---------------------------------------------------------------------------
__device__ __forceinline__ void gbarrier(unsigned* cnt, unsigned* iter, int gwg) {
    __syncthreads();
    if (threadIdx.x == 0) {
        __hip_atomic_fetch_add(cnt, 1u, __ATOMIC_RELAXED, __HIP_MEMORY_SCOPE_AGENT);
        const unsigned tgt = (*iter + 1u) * (unsigned)gwg;
        while (__hip_atomic_load(cnt, __ATOMIC_RELAXED, __HIP_MEMORY_SCOPE_AGENT) < tgt)
            ;
    }
    ++*iter;
    __syncthreads();
}

// ---------------------------------------------------------------------------
// Dtype sniffer + bars + FULL C-buffer zeroing (kills stale step-tags from
// prior graph replays — mandatory for the tagged-dataflow exchange).
// ---------------------------------------------------------------------------
__global__ void init_k(const uint32_t* __restrict__ emb_raw,
                       int* __restrict__ flag, unsigned* __restrict__ bars,
                       uint32_t* __restrict__ c0, uint32_t* __restrict__ c1) {
    const int t = blockIdx.x * 1024 + threadIdx.x;
    for (int k = t; k < NBARU; k += 8192) bars[k] = 0u;
    for (int k = t; k < NCU; k += 8192) { c0[k] = 0u; c1[k] = 0u; }
    if (t == 0) {
        uint32_t acc = 0;
        for (int i = 64; i < 128; ++i) acc |= emb_raw[i];
        *flag = (acc == 0u) ? 0 : 1;
    }
}

// ---------------------------------------------------------------------------
// G[c][j]: input-side gate pre-activations per class. j = q*512 + col,
// q in {0:f, 1:i, 2:o, 3:ctilde}; ctilde quarter pre-sigmoided.
// ---------------------------------------------------------------------------
template <bool BF>
__global__ void build_G(const int* __restrict__ flag,
                        const void* __restrict__ emb,
                        const void* __restrict__ Wfx, const void* __restrict__ Wix,
                        const void* __restrict__ Wox, const void* __restrict__ Wcx,
                        const void* __restrict__ bfv, const void* __restrict__ biv,
                        const void* __restrict__ bov, const void* __restrict__ bcv,
                        float* __restrict__ G) {
    if (*flag != (BF ? 1 : 0)) return;
    const int c   = blockIdx.x;
    const int j   = blockIdx.y * 256 + threadIdx.x;
    const int q   = j >> 9;
    const int col = j & 511;
    const void* W  = (q == 0) ? Wfx : (q == 1) ? Wix : (q == 2) ? Wox : Wcx;
    const void* bv = (q == 0) ? bfv : (q == 1) ? biv : (q == 2) ? bov : bcv;
    float acc = ldv<BF>(bv, col);
    for (int i = 0; i < ID; ++i)
        acc += ldv<BF>(emb, c * ID + i) * ldv<BF>(W, i * HD + col);
    if (q == 3) acc = sigf(acc);
    G[c * 2048 + j] = acc;
}

// ---------------------------------------------------------------------------
// Batch-split recurrence — r13 VERBATIM (standalone template instantiation
// restores the 1334us codegen). BF=false: r10 exchange (row-major tagged
// words, wave-local narrow-poll stage, scalar f32 dot) + single barrier/step
// (part2 double-buffered, [row][slot] conflict-free). BF=true: r8 tagged
// bf16 path.
// ---------------------------------------------------------------------------
template <bool BF>
__global__ __launch_bounds__(THR, 2) void recur_bs(
    const int* __restrict__ flag, const int* __restrict__ x,
    const float* __restrict__ G,
    const void* __restrict__ Wfc, const void* __restrict__ Wic,
    const void* __restrict__ Woc,
    float* __restrict__ C0, float* __restrict__ C1,
    float* __restrict__ Hfb, unsigned* __restrict__ bars)
{
    if (*flag != (BF ? 1 : 0)) return;

    __shared__ __align__(16) float Cs[RPGF * CPAD];       // 10.2 KB
    __shared__ __align__(16) uint32_t CbS[RPGB * CBW];    // 2.1 KB (bf16 path)
    __shared__ __align__(8)  float2 part2[2 * RPGF * PROW]; // 128.5 KB (2 bufs)
    __shared__ int idx[RPGF * TT];                        // 8 KB
    __shared__ int lz[RPGF];

    const int blk = blockIdx.x;
    const int tid = threadIdx.x;
    unsigned bi = 0;

    if constexpr (!BF) {
        // ===== f32 path: wave-local tagged dataflow (r13) =================
        const int grp   = blk >> 3;       // 0..31
        const int rank  = blk & 7;        // 0..7
        const int r0    = grp * RPGF;
        const int h0    = rank * COLSF;
        const int cp    = tid & 15;       // cols cp, +16, +32, +48
        const int chunk = tid >> 4;       // 0..31 (16 h' each)
        unsigned* bar = bars + grp * 32;  // startup barrier only

        // ---- stage x rows (2048 ints), find group start ----
        idx[tid]        = x[r0 * TT + tid];
        idx[tid + 512]  = x[r0 * TT + tid + 512];
        idx[tid + 1024] = x[r0 * TT + tid + 1024];
        idx[tid + 1536] = x[r0 * TT + tid + 1536];
        for (int k = tid; k < RPGF * CPAD; k += THR) Cs[k] = 0.0f;  // t0==TT edge
        if (tid < RPGF) lz[tid] = -1;
        __syncthreads();
        #pragma unroll
        for (int r = 0; r < RPGF; ++r)
            if (idx[r * TT + tid] == 0) atomicMax(&lz[r], tid);
        __syncthreads();
        int t0 = TT;
        #pragma unroll
        for (int r = 0; r < RPGF; ++r) t0 = min(t0, lz[r] + 1);
        // t0 is group-uniform.

        // ---- 128 pinned f32 weights: 4 cols x 2 gates x 16 h' ----
        float wf0[16], wf1[16], wf2[16], wf3[16];
        float wi0[16], wi1[16], wi2[16], wi3[16];
        #pragma unroll
        for (int k = 0; k < 16; ++k) {
            const int hp = chunk * 16 + k;
            wf0[k] = ldv<BF>(Wfc, hp * HD + h0 + cp);
            wf1[k] = ldv<BF>(Wfc, hp * HD + h0 + cp + 16);
            wf2[k] = ldv<BF>(Wfc, hp * HD + h0 + cp + 32);
            wf3[k] = ldv<BF>(Wfc, hp * HD + h0 + cp + 48);
            wi0[k] = ldv<BF>(Wic, hp * HD + h0 + cp);
            wi1[k] = ldv<BF>(Wic, hp * HD + h0 + cp + 16);
            wi2[k] = ldv<BF>(Wic, hp * HD + h0 + cp + 32);
            wi3[k] = ldv<BF>(Wic, hp * HD + h0 + cp + 48);
        }
        #pragma unroll
        for (int k = 0; k < 16; ++k)
            asm volatile("" : "+v"(wf0[k]), "+v"(wf1[k]), "+v"(wf2[k]), "+v"(wf3[k]),
                              "+v"(wi0[k]), "+v"(wi1[k]), "+v"(wi2[k]), "+v"(wi3[k]));

        const bool isUpd = (tid < COLSF * RPGF);
        const int uc = tid & 63, ur = tid >> 6;
        const int pe = cpi(tid);

        // ---- owner-init step tags (values 0), r10 row-major layout.
        // Active buf: tag t0; other buf: stale marker (t0+3)&3. ----
        {
            uint32_t* tA = (uint32_t*)((t0 & 1) ? C1 : C0);
            uint32_t* tB = (uint32_t*)((t0 & 1) ? C0 : C1);
            if (isUpd) {
                cstu(tA + (r0 + ur) * HD + h0 + uc, (uint32_t)(t0 & 3));
                cstu(tB + (r0 + ur) * HD + h0 + uc, (uint32_t)((t0 + 3) & 3));
            }
        }
        gbarrier(bar, &bi, GWGF);         // startup only: inits visible

        float Creg = 0.0f;
        for (int t = t0; t < TT; ++t) {
            // re-pin weights every iteration (r7/r8/r10 lesson)
            #pragma unroll
            for (int k = 0; k < 16; ++k)
                asm volatile("" : "+v"(wf0[k]), "+v"(wf1[k]), "+v"(wf2[k]), "+v"(wf3[k]),
                                  "+v"(wi0[k]), "+v"(wi1[k]), "+v"(wi2[k]), "+v"(wi3[k]));

            const uint32_t* curT = (const uint32_t*)((t & 1) ? C1 : C0);
            uint32_t*       nxtT = (uint32_t*)((t & 1) ? C0 : C1);

            // ---- prefetch G gate operands (in flight during the spin) ----
            float gf = 0.f, gi = 0.f, sgc = 0.f;
            int cl = 1;
            if (isUpd) {
                cl = idx[ur * TT + t];
                const float* Gr = G + cl * 2048;
                gf  = Gr[h0 + uc];
                gi  = Gr[512 + h0 + uc];
                sgc = Gr[1536 + h0 + uc];
            }

            // ---- WAVE-LOCAL stage: wave w spins only on rank-block w ----
            {
                const uint32_t* s0 = curT + (r0 + 0) * HD + tid;
                const uint32_t* s1 = curT + (r0 + 1) * HD + tid;
                const uint32_t* s2 = curT + (r0 + 2) * HD + tid;
                const uint32_t* s3 = curT + (r0 + 3) * HD + tid;
                const uint32_t exp = (uint32_t)t & 3u;
                uint32_t w0, w1, w2, w3;
                do { w0 = cldu(s0); } while ((w0 ^ exp) & 3u);
                for (;;) {
                    w1 = cldu(s1); w2 = cldu(s2); w3 = cldu(s3);
                    if ((((w1 ^ exp) | (w2 ^ exp) | (w3 ^ exp)) & 3u) == 0u)
                        break;
                }
                Cs[0 * CPAD + pe] = __uint_as_float(w0 & ~3u);
                Cs[1 * CPAD + pe] = __uint_as_float(w1 & ~3u);
                Cs[2 * CPAD + pe] = __uint_as_float(w2 & ~3u);
                Cs[3 * CPAD + pe] = __uint_as_float(w3 & ~3u);
            }
            // per-wave fence: same-wave DS ops complete in order.
            asm volatile("s_waitcnt lgkmcnt(0)" ::: "memory");

            // ---- dot over own block (scalar f32, r10-proven) ----
            float f0[RPGF], f1[RPGF], f2[RPGF], f3[RPGF];
            float i0[RPGF], i1[RPGF], i2[RPGF], i3[RPGF];
            #pragma unroll
            for (int r = 0; r < RPGF; ++r) {
                f0[r] = 0.f; f1[r] = 0.f; f2[r] = 0.f; f3[r] = 0.f;
                i0[r] = 0.f; i1[r] = 0.f; i2[r] = 0.f; i3[r] = 0.f;
            }
            {
                const int cb = chunk * 5;
                #pragma unroll
                for (int j = 0; j < 4; ++j) {
                    #pragma unroll
                    for (int r = 0; r < RPGF; ++r) {
                        const float4 cv = reinterpret_cast<const float4*>(
                            Cs + r * CPAD)[cb + j];
                        f0[r] += wf0[4*j]*cv.x + wf0[4*j+1]*cv.y + wf0[4*j+2]*cv.z + wf0[4*j+3]*cv.w;
                        f1[r] += wf1[4*j]*cv.x + wf1[4*j+1]*cv.y + wf1[4*j+2]*cv.z + wf1[4*j+3]*cv.w;
                        f2[r] += wf2[4*j]*cv.x + wf2[4*j+1]*cv.y + wf2[4*j+2]*cv.z + wf2[4*j+3]*cv.w;
                        f3[r] += wf3[4*j]*cv.x + wf3[4*j+1]*cv.y + wf3[4*j+2]*cv.z + wf3[4*j+3]*cv.w;
                        i0[r] += wi0[4*j]*cv.x + wi0[4*j+1]*cv.y + wi0[4*j+2]*cv.z + wi0[4*j+3]*cv.w;
                        i1[r] += wi1[4*j]*cv.x + wi1[4*j+1]*cv.y + wi1[4*j+2]*cv.z + wi1[4*j+3]*cv.w;
                        i2[r] += wi2[4*j]*cv.x + wi2[4*j+1]*cv.y + wi2[4*j+2]*cv.z + wi2[4*j+3]*cv.w;
                        i3[r] += wi3[4*j]*cv.x + wi3[4*j+1]*cv.y + wi3[4*j+2]*cv.z + wi3[4*j+3]*cv.w;
                    }
                }
            }

            // ---- write partials: buf[t&1], [row][slot] (lane-consecutive,
            // conflict-free). No pre-barrier needed (r13 proof). ----
            {
                float2* Pb = part2 + (t & 1) * (RPGF * PROW);
                #pragma unroll
                for (int r = 0; r < RPGF; ++r) {
                    float2* Pr = Pb + r * PROW + chunk * 64;
                    Pr[cp]      = make_float2(f0[r], i0[r]);
                    Pr[cp + 16] = make_float2(f1[r], i1[r]);
                    Pr[cp + 32] = make_float2(f2[r], i2[r]);
                    Pr[cp + 48] = make_float2(f3[r], i3[r]);
                }
            }
            __syncthreads();              // SINGLE barrier: partials ready

            // ---- update + tagged publish ----
            if (isUpd) {
                const float2* Pr = part2 + (t & 1) * (RPGF * PROW) + ur * PROW;
                float df = 0.f, di = 0.f;
                #pragma unroll
                for (int ch = 0; ch < 32; ++ch) {
                    const float2 v = Pr[ch * 64 + uc];
                    df += v.x;
                    di += v.y;
                }
                float Cn = sgc * sigf(gi + di) + Creg * sigf(gf + df);
                Cn = (cl > 0) ? Cn : 0.0f;
                Creg = Cn;
                cstu(nxtT + (r0 + ur) * HD + h0 + uc,
                     (__float_as_uint(Cn) & ~3u) | ((uint32_t)(t + 1) & 3u));
            }
            // no barrier, no drain: consumers spin on the in-word tag.
        }

        // ---- o-gate + h. Cs holds the carry entering step T-1 (staged at
        // the final iteration; zeros if t0==TT). o-dot is wave-local. ----
        __syncthreads();                  // last update's part2 reads done
        {
            const int oc = tid & 63, och = tid >> 6;
            float ao[RPGF];
            #pragma unroll
            for (int r = 0; r < RPGF; ++r) ao[r] = 0.0f;
            #pragma unroll 4
            for (int k = 0; k < 64; ++k) {
                const int hp = och * 64 + k;
                const int hpp = cpi(hp);
                const float wo = ldv<BF>(Woc, hp * HD + h0 + oc);
                #pragma unroll
                for (int r = 0; r < RPGF; ++r)
                    ao[r] += wo * Cs[r * CPAD + hpp];
            }
            {
                // buf 0, rows 0..1 hold the (row-pair) o-partials
                #pragma unroll
                for (int r2 = 0; r2 < RPGF / 2; ++r2)
                    part2[r2 * PROW + och * 64 + oc] =
                        make_float2(ao[2 * r2], ao[2 * r2 + 1]);
            }
            __syncthreads();
            if (isUpd) {
                const float2* Pr = part2 + (ur >> 1) * PROW;
                float s = 0.f;
                #pragma unroll
                for (int ch = 0; ch < 8; ++ch) {
                    const float2 v = Pr[ch * 64 + uc];
                    s += (ur & 1) ? v.y : v.x;
                }
                const int cl2 = idx[ur * TT + TT - 1];
                const float o = sigf(G[cl2 * 2048 + 1024 + h0 + uc] + s);
                Hfb[(r0 + ur) * HD + h0 + uc] = tanhf(Creg) * o;
            }
        }
    } else {
        // ===== bf16 path: r8 tagged dataflow ==============================
        const int grp   = blk >> 2;       // 0..63
        const int rank  = blk & 3;        // 0..3
        const int r0    = grp * RPGB;
        const int h0    = rank * COLSB;
        const int cp    = tid & 31;
        const int chunk = tid >> 5;

        idx[tid]       = x[r0 * TT + tid];
        idx[tid + 512] = x[r0 * TT + tid + 512];
        for (int k = tid; k < RPGB * CBW; k += THR) CbS[k] = 0u;
        if (tid < RPGB) lz[tid] = -1;
        __syncthreads();
        #pragma unroll
        for (int r = 0; r < RPGB; ++r)
            if (idx[r * TT + tid] == 0) atomicMax(&lz[r], tid);
        __syncthreads();
        int t0 = TT;
        #pragma unroll
        for (int r = 0; r < RPGB; ++r) t0 = min(t0, lz[r] + 1);

        const uint16_t* Wfr = (const uint16_t*)Wfc;
        const uint16_t* Wir = (const uint16_t*)Wic;
        uint32_t wf0[16], wf1[16], wf2[16], wf3[16];
        uint32_t wi0[16], wi1[16], wi2[16], wi3[16];
        #pragma unroll
        for (int p = 0; p < 16; ++p) {
            const int hp = chunk * 32 + 2 * p;
            const int b0 = hp * HD + h0 + cp, b1 = (hp + 1) * HD + h0 + cp;
            wf0[p] = (uint32_t)Wfr[b0]      | ((uint32_t)Wfr[b1]      << 16);
            wf1[p] = (uint32_t)Wfr[b0 + 32] | ((uint32_t)Wfr[b1 + 32] << 16);
            wf2[p] = (uint32_t)Wfr[b0 + 64] | ((uint32_t)Wfr[b1 + 64] << 16);
            wf3[p] = (uint32_t)Wfr[b0 + 96] | ((uint32_t)Wfr[b1 + 96] << 16);
            wi0[p] = (uint32_t)Wir[b0]      | ((uint32_t)Wir[b1]      << 16);
            wi1[p] = (uint32_t)Wir[b0 + 32] | ((uint32_t)Wir[b1 + 32] << 16);
            wi2[p] = (uint32_t)Wir[b0 + 64] | ((uint32_t)Wir[b1 + 64] << 16);
            wi3[p] = (uint32_t)Wir[b0 + 96] | ((uint32_t)Wir[b1 + 96] << 16);
        }
        #pragma unroll
        for (int p = 0; p < 16; ++p)
            asm volatile("" : "+v"(wf0[p]), "+v"(wf1[p]), "+v"(wf2[p]), "+v"(wf3[p]),
                              "+v"(wi0[p]), "+v"(wi1[p]), "+v"(wi2[p]), "+v"(wi3[p]));

        const bool isUpd = (tid < COLSB * RPGB);
        const int uc = tid & 127, ur = tid >> 7;

        if (isUpd && t0 > 0) {
            uint32_t* b0 = (uint32_t*)((t0 & 1) ? C1 : C0);
            cstu(b0 + (r0 + ur) * HD + h0 + uc, (uint32_t)t0 & 0xFFFFu);
        }

        float Creg = 0.0f;
        const int srow = tid >> 8;
        const int spr  = tid & 255;

        for (int t = t0; t < TT; ++t) {
            #pragma unroll
            for (int p = 0; p < 16; ++p)
                asm volatile("" : "+v"(wf0[p]), "+v"(wf1[p]), "+v"(wf2[p]), "+v"(wf3[p]),
                                  "+v"(wi0[p]), "+v"(wi1[p]), "+v"(wi2[p]), "+v"(wi3[p]));

            const uint32_t* curT = (const uint32_t*)((t & 1) ? C1 : C0);
            uint32_t*       nxtT = (uint32_t*)((t & 1) ? C0 : C1);

            float gf = 0.f, gi = 0.f, sgc = 0.f;
            int cl = 1;
            if (isUpd) {
                cl = idx[ur * TT + t];
                const float* Gr = G + cl * 2048;
                gf  = Gr[h0 + uc];
                gi  = Gr[512 + h0 + uc];
                sgc = Gr[1536 + h0 + uc];
            }

            {
                const uint64_t* src = (const uint64_t*)(
                    curT + (r0 + srow) * HD + 2 * spr);
                const uint32_t exp = (uint32_t)t & 0xFFFFu;
                uint32_t w0, w1;
                for (;;) {
                    const uint64_t d = cldu8(src);
                    w0 = (uint32_t)d;
                    w1 = (uint32_t)(d >> 32);
                    if ((((w0 ^ exp) | (w1 ^ exp)) & 0xFFFFu) == 0u) break;
                }
                CbS[srow * CBW + spr] = (w0 >> 16) | (w1 & 0xFFFF0000u);
            }
            __syncthreads();

            float f0[RPGB], f1[RPGB], f2[RPGB], f3[RPGB];
            float i0[RPGB], i1[RPGB], i2[RPGB], i3[RPGB];
            #pragma unroll
            for (int r = 0; r < RPGB; ++r) {
                f0[r] = 0.f; f1[r] = 0.f; f2[r] = 0.f; f3[r] = 0.f;
                i0[r] = 0.f; i1[r] = 0.f; i2[r] = 0.f; i3[r] = 0.f;
            }
            {
                const int cb = chunk * 16;
                #pragma unroll
                for (int hh = 0; hh < 4; ++hh) {
                    #pragma unroll
                    for (int r = 0; r < RPGB; ++r) {
                        const uint4 cv = *reinterpret_cast<const uint4*>(
                            CbS + r * CBW + cb + 4 * hh);
                        const int p = 4 * hh;
                        DOT2(f0[r], wf0[p + 0], cv.x); DOT2(f0[r], wf0[p + 1], cv.y);
                        DOT2(f0[r], wf0[p + 2], cv.z); DOT2(f0[r], wf0[p + 3], cv.w);
                        DOT2(f1[r], wf1[p + 0], cv.x); DOT2(f1[r], wf1[p + 1], cv.y);
                        DOT2(f1[r], wf1[p + 2], cv.z); DOT2(f1[r], wf1[p + 3], cv.w);
                        DOT2(f2[r], wf2[p + 0], cv.x); DOT2(f2[r], wf2[p + 1], cv.y);
                        DOT2(f2[r], wf2[p + 2], cv.z); DOT2(f2[r], wf2[p + 3], cv.w);
                        DOT2(f3[r], wf3[p + 0], cv.x); DOT2(f3[r], wf3[p + 1], cv.y);
                        DOT2(f3[r], wf3[p + 2], cv.z); DOT2(f3[r], wf3[p + 3], cv.w);
                        DOT2(i0[r], wi0[p + 0], cv.x); DOT2(i0[r], wi0[p + 1], cv.y);
                        DOT2(i0[r], wi0[p + 2], cv.z); DOT2(i0[r], wi0[p + 3], cv.w);
                        DOT2(i1[r], wi1[p + 0], cv.x); DOT2(i1[r], wi1[p + 1], cv.y);
                        DOT2(i1[r], wi1[p + 2], cv.z); DOT2(i1[r], wi1[p + 3], cv.w);
                        DOT2(i2[r], wi2[p + 0], cv.x); DOT2(i2[r], wi2[p + 1], cv.y);
                        DOT2(i2[r], wi2[p + 2], cv.z); DOT2(i2[r], wi2[p + 3], cv.w);
                        DOT2(i3[r], wi3[p + 0], cv.x); DOT2(i3[r], wi3[p + 1], cv.y);
                        DOT2(i3[r], wi3[p + 2], cv.z); DOT2(i3[r], wi3[p + 3], cv.w);
                    }
                }
            }
            {
                float2* part2b = (float2*)part2;
                float2* p0 = part2b + (chunk * 128 + cp)      * PSTB;
                float2* p1 = part2b + (chunk * 128 + cp + 32) * PSTB;
                float2* p2 = part2b + (chunk * 128 + cp + 64) * PSTB;
                float2* p3 = part2b + (chunk * 128 + cp + 96) * PSTB;
                #pragma unroll
                for (int r = 0; r < RPGB; ++r) {
                    p0[r] = make_float2(f0[r], i0[r]);
                    p1[r] = make_float2(f1[r], i1[r]);
                    p2[r] = make_float2(f2[r], i2[r]);
                    p3[r] = make_float2(f3[r], i3[r]);
                }
            }
            __syncthreads();

            if (isUpd) {
                float df = 0.f, di = 0.f;
                #pragma unroll
                for (int ch = 0; ch < 16; ++ch) {
                    const float2 v = part2[(ch * 128 + uc) * PSTB + ur];
                    df += v.x;
                    di += v.y;
                }
                float Cn = sgc * sigf(gi + di) + Creg * sigf(gf + df);
                Cn = (cl > 0) ? Cn : 0.0f;
                Creg = Cn;
                const uint32_t vb = pkbf(Cn, Cn);
                cstu(nxtT + (r0 + ur) * HD + h0 + uc,
                     (vb << 16) | ((uint32_t)(t + 1) & 0xFFFFu));
            }
        }

        __syncthreads();
        {
            const int rr = tid >> 8, wi = tid & 255;
            const uint32_t w = CbS[rr * CBW + wi];
            Cs[rr * CPAD + cpi(2 * wi)]     = __uint_as_float((w & 0xFFFFu) << 16);
            Cs[rr * CPAD + cpi(2 * wi + 1)] = __uint_as_float(w & 0xFFFF0000u);
            __syncthreads();

            const int oc = tid & 127, och = tid >> 7;
            float ao0 = 0.f, ao1 = 0.f;
            #pragma unroll 4
            for (int k = 0; k < 128; ++k) {
                const int hp  = och * 128 + k;
                const int hpp = cpi(hp);
                const float wo = ldv<BF>(Woc, hp * HD + h0 + oc);
                ao0 += wo * Cs[0 * CPAD + hpp];
                ao1 += wo * Cs[1 * CPAD + hpp];
            }
            part2[(och * 128 + oc) * PSTB] = make_float2(ao0, ao1);
            __syncthreads();
            if (isUpd) {
                float s = 0.f;
                #pragma unroll
                for (int ch = 0; ch < 4; ++ch) {
                    const float2 v = part2[(ch * 128 + uc) * PSTB];
                    s += ur ? v.y : v.x;
                }
                const int cl2 = idx[ur * TT + TT - 1];
                const float o = sigf(G[cl2 * 2048 + 1024 + h0 + uc] + s);
                Hfb[(r0 + ur) * HD + h0 + uc] = tanhf(Creg) * o;
            }
        }
    }
}

// ---------------------------------------------------------------------------
// Projection + log_softmax, one WG per batch row.
// ---------------------------------------------------------------------------
template <bool BF>
__global__ __launch_bounds__(128) void proj(
    const int* __restrict__ flag, const float* __restrict__ Hfb,
    const void* __restrict__ Wph, const void* __restrict__ bp,
    void* __restrict__ out)
{
    if (*flag != (BF ? 1 : 0)) return;
    __shared__ __align__(16) float hv[HD];
    __shared__ float p_s[NCLS];
    __shared__ float lse_s;
    const int b   = blockIdx.x;
    const int tid = threadIdx.x;

    reinterpret_cast<float4*>(hv)[tid] =
        reinterpret_cast<const float4*>(Hfb + b * HD)[tid];
    __syncthreads();

    if (tid < NCLS) {
        float p = ldv<BF>(bp, tid);
        for (int h = 0; h < HD; ++h)
            p += hv[h] * ldv<BF>(Wph, h * NCLS + tid);
        p_s[tid] = p;
    }
    __syncthreads();
    if (tid == 0) {
        float m = -1e30f;
        for (int n = 0; n < NCLS; ++n) m = fmaxf(m, p_s[n]);
        float sum = 0.0f;
        for (int n = 0; n < NCLS; ++n) sum += expf(p_s[n] - m);
        lse_s = m + logf(sum);
    }
    __syncthreads();
    if (tid < NCLS) {
        const float v = p_s[tid] - lse_s;
        if constexpr (BF) ((bf16*)out)[b * NCLS + tid] = __float2bfloat16(v);
        else              ((float*)out)[b * NCLS + tid] = v;
    }
}

// ---------------------------------------------------------------------------
extern "C" void kernel_launch(void* const* d_in, const int* in_sizes, int n_in,
                              void* d_out, int out_size, void* d_ws, size_t ws_size,
                              hipStream_t stream) {
    const int*  x   = (const int*)d_in[0];
    const void* emb = d_in[1];
    const void* Wfx = d_in[2];
    const void* Wfc = d_in[3];
    const void* bfv = d_in[4];
    const void* Wix = d_in[5];
    const void* Wic = d_in[6];
    const void* biv = d_in[7];
    const void* Wox = d_in[8];
    const void* Woc = d_in[9];
    const void* bov = d_in[10];
    const void* Wcx = d_in[11];
    const void* bcv = d_in[12];
    const void* Wph = d_in[13];
    const void* bp  = d_in[14];

    int*      flag = (int*)((char*)d_ws + WS_FLAG);
    unsigned* bars = (unsigned*)((char*)d_ws + WS_BAR);
    float*    G    = (float*)((char*)d_ws + WS_G);
    float*    C0   = (float*)((char*)d_ws + WS_C0);
    float*    C1   = (float*)((char*)d_ws + WS_C1);
    float*    Hfb  = (float*)((char*)d_ws + WS_HFB);

    // Host-side dtype discrimination from Wfc's size (512x512):
    //   HD*HD*4 bytes -> provably f32; HD*HD*2 bytes -> provably bf16;
    //   anything else (e.g. element counts) -> unknown, launch both
    //   flag-gated template sets (exact r13 behavior).
    const long long wfc_sz = (long long)in_sizes[3];
    const int kind = (wfc_sz == (long long)HD * HD * 4) ? 0
                   : (wfc_sz == (long long)HD * HD * 2) ? 1 : -1;

    init_k<<<8, 1024, 0, stream>>>((const uint32_t*)emb, flag, bars,
                                   (uint32_t*)C0, (uint32_t*)C1);

    if (kind != 1)
        build_G<false><<<dim3(NEMB, 8), 256, 0, stream>>>(flag, emb, Wfx, Wix, Wox, Wcx,
                                                          bfv, biv, bov, bcv, G);
    if (kind != 0)
        build_G<true ><<<dim3(NEMB, 8), 256, 0, stream>>>(flag, emb, Wfx, Wix, Wox, Wcx,
                                                          bfv, biv, bov, bcv, G);

    {
        void* args[] = {(void*)&flag, (void*)&x, (void*)&G,
                        (void*)&Wfc, (void*)&Wic, (void*)&Woc,
                        (void*)&C0, (void*)&C1, (void*)&Hfb, (void*)&bars};
        if (kind != 1)
            hipLaunchCooperativeKernel((const void*)recur_bs<false>, dim3(256), dim3(THR),
                                       args, 0, stream);
        if (kind != 0)
            hipLaunchCooperativeKernel((const void*)recur_bs<true>, dim3(256), dim3(THR),
                                       args, 0, stream);
    }

    if (kind != 1)
        proj<false><<<BB, 128, 0, stream>>>(flag, Hfb, Wph, bp, d_out);
    if (kind != 0)
        proj<true ><<<BB, 128, 0, stream>>>(flag, Hfb, Wph, bp, d_out);
}

// Round 16
// 1540.348 us; speedup vs baseline: 1.0189x; 1.0189x over previous
//
#include <hip/hip_runtime.h>
#include <hip/hip_bf16.h>
#include <stdint.h>

#define HD   512   // hidden dim H
#define ID   128   // input dim I
#define NCLS 100   // num classes
#define TT   512   // sequence length T
#define BB   128   // batch B
#define NEMB 101   // NC + 1 embedding rows
#define THR  512   // threads per recurrence WG (8 waves, 2 waves/SIMD)

// f32 geometry: 32 groups x 8 WGs x 64 cols, 4 rows/group.
#define NGRPF 32
#define GWGF  8
#define RPGF  4
#define COLSF 64
// bf16 geometry: 64 groups x 4 WGs x 128 cols, 2 rows/group.
#define NGRPB 64
#define GWGB  4
#define RPGB  2
#define COLSB 128

#define CPAD 640   // f32 LDS C row stride (32 chunks x (16 data + 4 pad))
#define CBW  260   // packed-bf16 C row stride in u32 (256 pairs + 4 pad)
#define PROW 2056  // f32 partials row stride in float2 (2048 slots + 8 pad)
#define PSTB 3     // bf16-path partials stride in float2

// workspace layout (bytes)
#define WS_BAR  4096                   // u32 bars[4096] (zeroed by build_G_k)
#define WS_G    65536                  // float G[101][2048]  (808 KB)
#define WS_C0   (1u * 1024 * 1024)     // C0: tagged u32 exchange buffer
#define WS_C1   (WS_C0 + 262144)
#define WS_HFB  (WS_C1 + 262144)       // float Hfb[128][512] (256 KB)
#define NBARU   4096

using bf16 = __hip_bfloat16;

__device__ __forceinline__ float b2f(bf16 v) { return __bfloat162float(v); }
__device__ __forceinline__ float sigf(float x) { return 1.0f / (1.0f + expf(-x)); }

// Agent-scope accessors — proven (die-level coherence point).
// LEDGER:
//  r1: separate flag+data exchange — lost to central RMW.
//  r3/r4: sc0 same-XCD L2 transport — stale L1; refuted. Do not retry.
//  r5: ext_vector v2f — hipcc scalarizes.
//  r6-r8 "nulls" VOID: flag=0 (inputs f32); bf16-path edits were dead.
//  r9: tagged dataflow (2-bit step tag in mantissa) — WIN 1469->1375.
//  r10/r11: wave-local stage, pk_fma — NULL: compute off critical chain.
//  r12: [col][4row] repack — REGRESSION: broke publish coalescing.
//  r13: single barrier/step + [row][slot] partials — WIN (recur "1334").
//  r14: dispatch merge (runtime branch) — total 1420, recur 1401.
//  r15: host-side size discrimination FAILED (in_sizes not bytes; total
//      1569 = 7-dispatch behavior) AND exposed that r13's 1334 was session
//      variance: r13-verbatim source measured 1403 = r14's 1401. The
//      merged kernel has NO codegen tax; r14 is the true best (1420).
//  r16 (this round): 2 DISPATCHES. init_k deleted: (a) C-zeroing redundant
//      — owner-init covers EVERY polled word of both buffers before the
//      startup gbarrier (bf16 path upgraded to the same discipline with a
//      0xFFFF stale-marker + its own startup gbarrier); (b) bars zeroing
//      folded into build_G_k block(0,0) (dispatch boundary = visibility);
//      (c) dtype flag computed in-kernel (64-word emb probe). proj fused
//      into the recurrence epilogue: Hfb via cst -> group gbarrier ->
//      rank0 stages via cld (agent; stale-L1-proof) -> identical proj
//      math -> out. build_G stays separate (its boundary flushes G for
//      the recurrence's plain loads).
__device__ __forceinline__ float cld(const float* p) {
    return __hip_atomic_load(p, __ATOMIC_RELAXED, __HIP_MEMORY_SCOPE_AGENT);
}
__device__ __forceinline__ void cst(float* p, float v) {
    __hip_atomic_store(p, v, __ATOMIC_RELAXED, __HIP_MEMORY_SCOPE_AGENT);
}
__device__ __forceinline__ void cstu(uint32_t* p, uint32_t v) {
    __hip_atomic_store(p, v, __ATOMIC_RELAXED, __HIP_MEMORY_SCOPE_AGENT);
}
__device__ __forceinline__ uint32_t cldu(const uint32_t* p) {
    return __hip_atomic_load(p, __ATOMIC_RELAXED, __HIP_MEMORY_SCOPE_AGENT);
}
__device__ __forceinline__ uint64_t cldu8(const uint64_t* p) {
    return __hip_atomic_load(p, __ATOMIC_RELAXED, __HIP_MEMORY_SCOPE_AGENT);
}

// pack two f32 into bf16x2 (low = first arg) — gfx950-verified instruction
__device__ __forceinline__ uint32_t pkbf(float x, float y) {
    uint32_t u;
    asm("v_cvt_pk_bf16_f32 %0, %1, %2" : "=v"(u) : "v"(x), "v"(y));
    return u;
}
// 2-way bf16 dot with f32 accumulate (VOP3P) — schedulable.
#define DOT2(acc, w, c) \
    asm("v_dot2_f32_bf16 %0, %1, %2, %0" : "+v"(acc) : "v"(w), "v"(c))

template <bool BF>
__device__ __forceinline__ float ldv(const void* p, int i) {
    if constexpr (BF) return b2f(((const bf16*)p)[i]);
    else              return ((const float*)p)[i];
}

// padded f32 Cs index for h' (16 data floats + 4 pad per chunk)
__device__ __forceinline__ int cpi(int h) { return (h >> 4) * 20 + (h & 15); }

// ---------------------------------------------------------------------------
// Group barrier — startup/epilogue only (per-step barriers deleted since r9).
// bars are zeroed each launch by build_G_k (replay-safe counters).
// ---------------------------------------------------------------------------
__device__ __forceinline__ void gbarrier(unsigned* cnt, unsigned* iter, int gwg) {
    __syncthreads();
    if (threadIdx.x == 0) {
        __hip_atomic_fetch_add(cnt, 1u, __ATOMIC_RELAXED, __HIP_MEMORY_SCOPE_AGENT);
        const unsigned tgt = (*iter + 1u) * (unsigned)gwg;
        while (__hip_atomic_load(cnt, __ATOMIC_RELAXED, __HIP_MEMORY_SCOPE_AGENT) < tgt)
            ;
    }
    ++*iter;
    __syncthreads();
}

// In-kernel dtype probe: emb bytes [256,512) are zero iff f32 (row 0 is
// exactly 0.0 by construction; bf16 row 1 occupies those bytes, nonzero).
__device__ __forceinline__ int probe_flag(const uint32_t* emb_raw,
                                          uint32_t* accS) {
    if (threadIdx.x == 0) *accS = 0u;
    __syncthreads();
    if (threadIdx.x < 64 && emb_raw[64 + threadIdx.x] != 0u)
        atomicOr(accS, 1u);
    __syncthreads();
    return (*accS != 0u) ? 1 : 0;
}

// ---------------------------------------------------------------------------
// G[c][j]: input-side gate pre-activations per class. j = q*512 + col,
// q in {0:f, 1:i, 2:o, 3:ctilde}; ctilde quarter pre-sigmoided.
// Merged runtime-dtype kernel; block (0,0) also zeroes bars for this launch.
// ---------------------------------------------------------------------------
template <bool BF>
__device__ __forceinline__ void build_G_body(
    const void* emb, const void* Wfx, const void* Wix,
    const void* Wox, const void* Wcx,
    const void* bfv, const void* biv, const void* bov, const void* bcv,
    float* G) {
    const int c   = blockIdx.x;
    const int j   = blockIdx.y * 256 + threadIdx.x;
    const int q   = j >> 9;
    const int col = j & 511;
    const void* W  = (q == 0) ? Wfx : (q == 1) ? Wix : (q == 2) ? Wox : Wcx;
    const void* bv = (q == 0) ? bfv : (q == 1) ? biv : (q == 2) ? bov : bcv;
    float acc = ldv<BF>(bv, col);
    #pragma unroll 4
    for (int i = 0; i < ID; ++i)
        acc += ldv<BF>(emb, c * ID + i) * ldv<BF>(W, i * HD + col);
    if (q == 3) acc = sigf(acc);
    G[c * 2048 + j] = acc;
}

__global__ void build_G_k(const void* __restrict__ emb,
                          const void* __restrict__ Wfx, const void* __restrict__ Wix,
                          const void* __restrict__ Wox, const void* __restrict__ Wcx,
                          const void* __restrict__ bfv, const void* __restrict__ biv,
                          const void* __restrict__ bov, const void* __restrict__ bcv,
                          float* __restrict__ G, unsigned* __restrict__ bars) {
    __shared__ uint32_t accS;
    // bars zeroing (block 0,0): visible to recur_fused via dispatch boundary.
    if (blockIdx.x == 0 && blockIdx.y == 0)
        for (int k = threadIdx.x; k < NBARU; k += 256) bars[k] = 0u;
    const int fl = probe_flag((const uint32_t*)emb, &accS);
    if (fl == 0) build_G_body<false>(emb, Wfx, Wix, Wox, Wcx, bfv, biv, bov, bcv, G);
    else         build_G_body<true >(emb, Wfx, Wix, Wox, Wcx, bfv, biv, bov, bcv, G);
}

// ---------------------------------------------------------------------------
// FUSED recurrence + projection (single cooperative dispatch). Runtime
// dtype branch (r14-proven: no codegen tax). f32 hot loop = r13 verbatim:
// tagged dataflow (2-bit step tag), wave-local narrow-poll stage, scalar
// f32 dot, single barrier/step with double-buffered [row][slot] partials.
// Epilogue: o-gate -> Hfb via cst -> group gbarrier -> rank0 projects its
// rows (identical math to the old proj kernel) -> log_softmax -> out.
// ---------------------------------------------------------------------------
__global__ __launch_bounds__(THR, 2) void recur_fused(
    const int* __restrict__ x, const float* __restrict__ G,
    const void* __restrict__ Wfc, const void* __restrict__ Wic,
    const void* __restrict__ Woc,
    float* __restrict__ C0, float* __restrict__ C1,
    float* __restrict__ Hfb, unsigned* __restrict__ bars,
    const void* __restrict__ emb,
    const void* __restrict__ Wph, const void* __restrict__ bp,
    void* __restrict__ out)
{
    __shared__ __align__(16) float Cs[RPGF * CPAD];       // 10.2 KB
    __shared__ __align__(16) uint32_t CbS[RPGB * CBW];    // 2.1 KB (bf16 path)
    __shared__ __align__(8)  float2 part2[2 * RPGF * PROW]; // 128.5 KB
    __shared__ int idx[RPGF * TT];                        // 8 KB
    __shared__ int lz[RPGF];
    __shared__ uint32_t accS;
    __shared__ float lseS[RPGF];

    const int blk = blockIdx.x;
    const int tid = threadIdx.x;
    unsigned bi = 0;
    const int fl = probe_flag((const uint32_t*)emb, &accS);

    if (fl == 0) {
        // ===== f32 path (LIVE): wave-local tagged dataflow (r13) ==========
        const int grp   = blk >> 3;       // 0..31
        const int rank  = blk & 7;        // 0..7
        const int r0    = grp * RPGF;
        const int h0    = rank * COLSF;
        const int cp    = tid & 15;       // cols cp, +16, +32, +48
        const int chunk = tid >> 4;       // 0..31 (16 h' each)
        unsigned* bar = bars + grp * 32;

        // ---- stage x rows (2048 ints), find group start ----
        idx[tid]        = x[r0 * TT + tid];
        idx[tid + 512]  = x[r0 * TT + tid + 512];
        idx[tid + 1024] = x[r0 * TT + tid + 1024];
        idx[tid + 1536] = x[r0 * TT + tid + 1536];
        for (int k = tid; k < RPGF * CPAD; k += THR) Cs[k] = 0.0f;  // t0==TT edge
        if (tid < RPGF) lz[tid] = -1;
        __syncthreads();
        #pragma unroll
        for (int r = 0; r < RPGF; ++r)
            if (idx[r * TT + tid] == 0) atomicMax(&lz[r], tid);
        __syncthreads();
        int t0 = TT;
        #pragma unroll
        for (int r = 0; r < RPGF; ++r) t0 = min(t0, lz[r] + 1);
        // t0 is group-uniform.

        // ---- 128 pinned f32 weights: 4 cols x 2 gates x 16 h' ----
        float wf0[16], wf1[16], wf2[16], wf3[16];
        float wi0[16], wi1[16], wi2[16], wi3[16];
        #pragma unroll
        for (int k = 0; k < 16; ++k) {
            const int hp = chunk * 16 + k;
            wf0[k] = ldv<false>(Wfc, hp * HD + h0 + cp);
            wf1[k] = ldv<false>(Wfc, hp * HD + h0 + cp + 16);
            wf2[k] = ldv<false>(Wfc, hp * HD + h0 + cp + 32);
            wf3[k] = ldv<false>(Wfc, hp * HD + h0 + cp + 48);
            wi0[k] = ldv<false>(Wic, hp * HD + h0 + cp);
            wi1[k] = ldv<false>(Wic, hp * HD + h0 + cp + 16);
            wi2[k] = ldv<false>(Wic, hp * HD + h0 + cp + 32);
            wi3[k] = ldv<false>(Wic, hp * HD + h0 + cp + 48);
        }
        #pragma unroll
        for (int k = 0; k < 16; ++k)
            asm volatile("" : "+v"(wf0[k]), "+v"(wf1[k]), "+v"(wf2[k]), "+v"(wf3[k]),
                              "+v"(wi0[k]), "+v"(wi1[k]), "+v"(wi2[k]), "+v"(wi3[k]));

        const bool isUpd = (tid < COLSF * RPGF);
        const int uc = tid & 63, ur = tid >> 6;
        const int pe = cpi(tid);

        // ---- owner-init step tags (values 0). Covers EVERY polled word of
        // both buffers (8 ranks x own slice = full group slice) BEFORE the
        // startup barrier -> poisoned workspace is never observed; init_k's
        // zeroing is redundant. Active buf: tag t0; other: (t0+3)&3. ----
        {
            uint32_t* tA = (uint32_t*)((t0 & 1) ? C1 : C0);
            uint32_t* tB = (uint32_t*)((t0 & 1) ? C0 : C1);
            if (isUpd) {
                cstu(tA + (r0 + ur) * HD + h0 + uc, (uint32_t)(t0 & 3));
                cstu(tB + (r0 + ur) * HD + h0 + uc, (uint32_t)((t0 + 3) & 3));
            }
        }
        gbarrier(bar, &bi, GWGF);         // startup: inits visible

        float Creg = 0.0f;
        for (int t = t0; t < TT; ++t) {
            // re-pin weights every iteration (r7/r8/r10 lesson)
            #pragma unroll
            for (int k = 0; k < 16; ++k)
                asm volatile("" : "+v"(wf0[k]), "+v"(wf1[k]), "+v"(wf2[k]), "+v"(wf3[k]),
                                  "+v"(wi0[k]), "+v"(wi1[k]), "+v"(wi2[k]), "+v"(wi3[k]));

            const uint32_t* curT = (const uint32_t*)((t & 1) ? C1 : C0);
            uint32_t*       nxtT = (uint32_t*)((t & 1) ? C0 : C1);

            // ---- prefetch G gate operands (in flight during the spin) ----
            float gf = 0.f, gi = 0.f, sgc = 0.f;
            int cl = 1;
            if (isUpd) {
                cl = idx[ur * TT + t];
                const float* Gr = G + cl * 2048;
                gf  = Gr[h0 + uc];
                gi  = Gr[512 + h0 + uc];
                sgc = Gr[1536 + h0 + uc];
            }

            // ---- WAVE-LOCAL stage: wave w spins only on rank-block w ----
            {
                const uint32_t* s0 = curT + (r0 + 0) * HD + tid;
                const uint32_t* s1 = curT + (r0 + 1) * HD + tid;
                const uint32_t* s2 = curT + (r0 + 2) * HD + tid;
                const uint32_t* s3 = curT + (r0 + 3) * HD + tid;
                const uint32_t exp = (uint32_t)t & 3u;
                uint32_t w0, w1, w2, w3;
                do { w0 = cldu(s0); } while ((w0 ^ exp) & 3u);
                for (;;) {
                    w1 = cldu(s1); w2 = cldu(s2); w3 = cldu(s3);
                    if ((((w1 ^ exp) | (w2 ^ exp) | (w3 ^ exp)) & 3u) == 0u)
                        break;
                }
                Cs[0 * CPAD + pe] = __uint_as_float(w0 & ~3u);
                Cs[1 * CPAD + pe] = __uint_as_float(w1 & ~3u);
                Cs[2 * CPAD + pe] = __uint_as_float(w2 & ~3u);
                Cs[3 * CPAD + pe] = __uint_as_float(w3 & ~3u);
            }
            // per-wave fence: same-wave DS ops complete in order.
            asm volatile("s_waitcnt lgkmcnt(0)" ::: "memory");

            // ---- dot over own block (scalar f32, r10-proven) ----
            float f0[RPGF], f1[RPGF], f2[RPGF], f3[RPGF];
            float i0[RPGF], i1[RPGF], i2[RPGF], i3[RPGF];
            #pragma unroll
            for (int r = 0; r < RPGF; ++r) {
                f0[r] = 0.f; f1[r] = 0.f; f2[r] = 0.f; f3[r] = 0.f;
                i0[r] = 0.f; i1[r] = 0.f; i2[r] = 0.f; i3[r] = 0.f;
            }
            {
                const int cb = chunk * 5;
                #pragma unroll
                for (int j = 0; j < 4; ++j) {
                    #pragma unroll
                    for (int r = 0; r < RPGF; ++r) {
                        const float4 cv = reinterpret_cast<const float4*>(
                            Cs + r * CPAD)[cb + j];
                        f0[r] += wf0[4*j]*cv.x + wf0[4*j+1]*cv.y + wf0[4*j+2]*cv.z + wf0[4*j+3]*cv.w;
                        f1[r] += wf1[4*j]*cv.x + wf1[4*j+1]*cv.y + wf1[4*j+2]*cv.z + wf1[4*j+3]*cv.w;
                        f2[r] += wf2[4*j]*cv.x + wf2[4*j+1]*cv.y + wf2[4*j+2]*cv.z + wf2[4*j+3]*cv.w;
                        f3[r] += wf3[4*j]*cv.x + wf3[4*j+1]*cv.y + wf3[4*j+2]*cv.z + wf3[4*j+3]*cv.w;
                        i0[r] += wi0[4*j]*cv.x + wi0[4*j+1]*cv.y + wi0[4*j+2]*cv.z + wi0[4*j+3]*cv.w;
                        i1[r] += wi1[4*j]*cv.x + wi1[4*j+1]*cv.y + wi1[4*j+2]*cv.z + wi1[4*j+3]*cv.w;
                        i2[r] += wi2[4*j]*cv.x + wi2[4*j+1]*cv.y + wi2[4*j+2]*cv.z + wi2[4*j+3]*cv.w;
                        i3[r] += wi3[4*j]*cv.x + wi3[4*j+1]*cv.y + wi3[4*j+2]*cv.z + wi3[4*j+3]*cv.w;
                    }
                }
            }

            // ---- write partials: buf[t&1], [row][slot] (conflict-free) ----
            {
                float2* Pb = part2 + (t & 1) * (RPGF * PROW);
                #pragma unroll
                for (int r = 0; r < RPGF; ++r) {
                    float2* Pr = Pb + r * PROW + chunk * 64;
                    Pr[cp]      = make_float2(f0[r], i0[r]);
                    Pr[cp + 16] = make_float2(f1[r], i1[r]);
                    Pr[cp + 32] = make_float2(f2[r], i2[r]);
                    Pr[cp + 48] = make_float2(f3[r], i3[r]);
                }
            }
            __syncthreads();              // SINGLE barrier: partials ready

            // ---- update + tagged publish ----
            if (isUpd) {
                const float2* Pr = part2 + (t & 1) * (RPGF * PROW) + ur * PROW;
                float df = 0.f, di = 0.f;
                #pragma unroll
                for (int ch = 0; ch < 32; ++ch) {
                    const float2 v = Pr[ch * 64 + uc];
                    df += v.x;
                    di += v.y;
                }
                float Cn = sgc * sigf(gi + di) + Creg * sigf(gf + df);
                Cn = (cl > 0) ? Cn : 0.0f;
                Creg = Cn;
                cstu(nxtT + (r0 + ur) * HD + h0 + uc,
                     (__float_as_uint(Cn) & ~3u) | ((uint32_t)(t + 1) & 3u));
            }
            // no barrier, no drain: consumers spin on the in-word tag.
        }

        // ---- o-gate + h. Cs holds the carry entering step T-1. ----
        __syncthreads();                  // last update's part2 reads done
        {
            const int oc = tid & 63, och = tid >> 6;
            float ao[RPGF];
            #pragma unroll
            for (int r = 0; r < RPGF; ++r) ao[r] = 0.0f;
            #pragma unroll 4
            for (int k = 0; k < 64; ++k) {
                const int hp = och * 64 + k;
                const int hpp = cpi(hp);
                const float wo = ldv<false>(Woc, hp * HD + h0 + oc);
                #pragma unroll
                for (int r = 0; r < RPGF; ++r)
                    ao[r] += wo * Cs[r * CPAD + hpp];
            }
            {
                #pragma unroll
                for (int r2 = 0; r2 < RPGF / 2; ++r2)
                    part2[r2 * PROW + och * 64 + oc] =
                        make_float2(ao[2 * r2], ao[2 * r2 + 1]);
            }
            __syncthreads();
            if (isUpd) {
                const float2* Pr = part2 + (ur >> 1) * PROW;
                float s = 0.f;
                #pragma unroll
                for (int ch = 0; ch < 8; ++ch) {
                    const float2 v = Pr[ch * 64 + uc];
                    s += (ur & 1) ? v.y : v.x;
                }
                const int cl2 = idx[ur * TT + TT - 1];
                const float o = sigf(G[cl2 * 2048 + 1024 + h0 + uc] + s);
                cst(&Hfb[(r0 + ur) * HD + h0 + uc], tanhf(Creg) * o);
            }
        }

        // ---- FUSED projection: Hfb visible after group barrier; rank 0
        // projects its 4 rows (identical math to the old proj kernel). ----
        gbarrier(bar, &bi, GWGF);         // Hfb stores drained + visible
        if (rank == 0) {
            float* hv = (float*)part2;    // [4][512] staged h
            hv[0 * 512 + tid] = cld(Hfb + (r0 + 0) * HD + tid);
            hv[1 * 512 + tid] = cld(Hfb + (r0 + 1) * HD + tid);
            hv[2 * 512 + tid] = cld(Hfb + (r0 + 2) * HD + tid);
            hv[3 * 512 + tid] = cld(Hfb + (r0 + 3) * HD + tid);
            __syncthreads();
            const int row = tid >> 7, c = tid & 127;   // 4 x 128
            float p = -1e30f;
            if (c < NCLS) {
                p = ldv<false>(bp, c);
                const float* hr = hv + row * 512;
                for (int h = 0; h < HD; ++h)
                    p += hr[h] * ldv<false>(Wph, h * NCLS + c);
            }
            float* ps = hv + 4 * 512;     // [4][128] logits
            ps[row * 128 + c] = p;
            __syncthreads();
            if (c == 0) {
                const float* pr = ps + row * 128;
                float m = -1e30f;
                for (int n = 0; n < NCLS; ++n) m = fmaxf(m, pr[n]);
                float sum = 0.0f;
                for (int n = 0; n < NCLS; ++n) sum += expf(pr[n] - m);
                lseS[row] = m + logf(sum);
            }
            __syncthreads();
            if (c < NCLS)
                ((float*)out)[(r0 + row) * NCLS + c] = ps[row * 128 + c] - lseS[row];
        }
    } else {
        // ===== bf16 path: r8 tagged dataflow + same fold discipline =======
        const int grp   = blk >> 2;       // 0..63
        const int rank  = blk & 3;        // 0..3
        const int r0    = grp * RPGB;
        const int h0    = rank * COLSB;
        const int cp    = tid & 31;
        const int chunk = tid >> 5;
        unsigned* bar = bars + grp * 32;

        idx[tid]       = x[r0 * TT + tid];
        idx[tid + 512] = x[r0 * TT + tid + 512];
        for (int k = tid; k < RPGB * CBW; k += THR) CbS[k] = 0u;
        if (tid < RPGB) lz[tid] = -1;
        __syncthreads();
        #pragma unroll
        for (int r = 0; r < RPGB; ++r)
            if (idx[r * TT + tid] == 0) atomicMax(&lz[r], tid);
        __syncthreads();
        int t0 = TT;
        #pragma unroll
        for (int r = 0; r < RPGB; ++r) t0 = min(t0, lz[r] + 1);

        const uint16_t* Wfr = (const uint16_t*)Wfc;
        const uint16_t* Wir = (const uint16_t*)Wic;
        uint32_t wf0[16], wf1[16], wf2[16], wf3[16];
        uint32_t wi0[16], wi1[16], wi2[16], wi3[16];
        #pragma unroll
        for (int p = 0; p < 16; ++p) {
            const int hp = chunk * 32 + 2 * p;
            const int b0 = hp * HD + h0 + cp, b1 = (hp + 1) * HD + h0 + cp;
            wf0[p] = (uint32_t)Wfr[b0]      | ((uint32_t)Wfr[b1]      << 16);
            wf1[p] = (uint32_t)Wfr[b0 + 32] | ((uint32_t)Wfr[b1 + 32] << 16);
            wf2[p] = (uint32_t)Wfr[b0 + 64] | ((uint32_t)Wfr[b1 + 64] << 16);
            wf3[p] = (uint32_t)Wfr[b0 + 96] | ((uint32_t)Wfr[b1 + 96] << 16);
            wi0[p] = (uint32_t)Wir[b0]      | ((uint32_t)Wir[b1]      << 16);
            wi1[p] = (uint32_t)Wir[b0 + 32] | ((uint32_t)Wir[b1 + 32] << 16);
            wi2[p] = (uint32_t)Wir[b0 + 64] | ((uint32_t)Wir[b1 + 64] << 16);
            wi3[p] = (uint32_t)Wir[b0 + 96] | ((uint32_t)Wir[b1 + 96] << 16);
        }
        #pragma unroll
        for (int p = 0; p < 16; ++p)
            asm volatile("" : "+v"(wf0[p]), "+v"(wf1[p]), "+v"(wf2[p]), "+v"(wf3[p]),
                              "+v"(wi0[p]), "+v"(wi1[p]), "+v"(wi2[p]), "+v"(wi3[p]));

        const bool isUpd = (tid < COLSB * RPGB);
        const int uc = tid & 127, ur = tid >> 7;

        // owner-init BOTH buffers (replaces init_k zeroing): active buf
        // tag t0 (value bf16(0)=0 high half); other buf stale marker
        // 0xFFFF (> any consumed tag <= TT). Startup gbarrier follows.
        if (isUpd) {
            uint32_t* bufA = (uint32_t*)((t0 & 1) ? C1 : C0);
            uint32_t* bufB = (uint32_t*)((t0 & 1) ? C0 : C1);
            cstu(bufA + (r0 + ur) * HD + h0 + uc, (uint32_t)t0 & 0xFFFFu);
            cstu(bufB + (r0 + ur) * HD + h0 + uc, 0xFFFFu);
        }
        gbarrier(bar, &bi, GWGB);

        float Creg = 0.0f;
        const int srow = tid >> 8;
        const int spr  = tid & 255;

        for (int t = t0; t < TT; ++t) {
            #pragma unroll
            for (int p = 0; p < 16; ++p)
                asm volatile("" : "+v"(wf0[p]), "+v"(wf1[p]), "+v"(wf2[p]), "+v"(wf3[p]),
                                  "+v"(wi0[p]), "+v"(wi1[p]), "+v"(wi2[p]), "+v"(wi3[p]));

            const uint32_t* curT = (const uint32_t*)((t & 1) ? C1 : C0);
            uint32_t*       nxtT = (uint32_t*)((t & 1) ? C0 : C1);

            float gf = 0.f, gi = 0.f, sgc = 0.f;
            int cl = 1;
            if (isUpd) {
                cl = idx[ur * TT + t];
                const float* Gr = G + cl * 2048;
                gf  = Gr[h0 + uc];
                gi  = Gr[512 + h0 + uc];
                sgc = Gr[1536 + h0 + uc];
            }

            {
                const uint64_t* src = (const uint64_t*)(
                    curT + (r0 + srow) * HD + 2 * spr);
                const uint32_t exp = (uint32_t)t & 0xFFFFu;
                uint32_t w0, w1;
                for (;;) {
                    const uint64_t d = cldu8(src);
                    w0 = (uint32_t)d;
                    w1 = (uint32_t)(d >> 32);
                    if ((((w0 ^ exp) | (w1 ^ exp)) & 0xFFFFu) == 0u) break;
                }
                CbS[srow * CBW + spr] = (w0 >> 16) | (w1 & 0xFFFF0000u);
            }
            __syncthreads();

            float f0[RPGB], f1[RPGB], f2[RPGB], f3[RPGB];
            float i0[RPGB], i1[RPGB], i2[RPGB], i3[RPGB];
            #pragma unroll
            for (int r = 0; r < RPGB; ++r) {
                f0[r] = 0.f; f1[r] = 0.f; f2[r] = 0.f; f3[r] = 0.f;
                i0[r] = 0.f; i1[r] = 0.f; i2[r] = 0.f; i3[r] = 0.f;
            }
            {
                const int cb = chunk * 16;
                #pragma unroll
                for (int hh = 0; hh < 4; ++hh) {
                    #pragma unroll
                    for (int r = 0; r < RPGB; ++r) {
                        const uint4 cv = *reinterpret_cast<const uint4*>(
                            CbS + r * CBW + cb + 4 * hh);
                        const int p = 4 * hh;
                        DOT2(f0[r], wf0[p + 0], cv.x); DOT2(f0[r], wf0[p + 1], cv.y);
                        DOT2(f0[r], wf0[p + 2], cv.z); DOT2(f0[r], wf0[p + 3], cv.w);
                        DOT2(f1[r], wf1[p + 0], cv.x); DOT2(f1[r], wf1[p + 1], cv.y);
                        DOT2(f1[r], wf1[p + 2], cv.z); DOT2(f1[r], wf1[p + 3], cv.w);
                        DOT2(f2[r], wf2[p + 0], cv.x); DOT2(f2[r], wf2[p + 1], cv.y);
                        DOT2(f2[r], wf2[p + 2], cv.z); DOT2(f2[r], wf2[p + 3], cv.w);
                        DOT2(f3[r], wf3[p + 0], cv.x); DOT2(f3[r], wf3[p + 1], cv.y);
                        DOT2(f3[r], wf3[p + 2], cv.z); DOT2(f3[r], wf3[p + 3], cv.w);
                        DOT2(i0[r], wi0[p + 0], cv.x); DOT2(i0[r], wi0[p + 1], cv.y);
                        DOT2(i0[r], wi0[p + 2], cv.z); DOT2(i0[r], wi0[p + 3], cv.w);
                        DOT2(i1[r], wi1[p + 0], cv.x); DOT2(i1[r], wi1[p + 1], cv.y);
                        DOT2(i1[r], wi1[p + 2], cv.z); DOT2(i1[r], wi1[p + 3], cv.w);
                        DOT2(i2[r], wi2[p + 0], cv.x); DOT2(i2[r], wi2[p + 1], cv.y);
                        DOT2(i2[r], wi2[p + 2], cv.z); DOT2(i2[r], wi2[p + 3], cv.w);
                        DOT2(i3[r], wi3[p + 0], cv.x); DOT2(i3[r], wi3[p + 1], cv.y);
                        DOT2(i3[r], wi3[p + 2], cv.z); DOT2(i3[r], wi3[p + 3], cv.w);
                    }
                }
            }
            {
                float2* part2b = (float2*)part2;
                float2* p0 = part2b + (chunk * 128 + cp)      * PSTB;
                float2* p1 = part2b + (chunk * 128 + cp + 32) * PSTB;
                float2* p2 = part2b + (chunk * 128 + cp + 64) * PSTB;
                float2* p3 = part2b + (chunk * 128 + cp + 96) * PSTB;
                #pragma unroll
                for (int r = 0; r < RPGB; ++r) {
                    p0[r] = make_float2(f0[r], i0[r]);
                    p1[r] = make_float2(f1[r], i1[r]);
                    p2[r] = make_float2(f2[r], i2[r]);
                    p3[r] = make_float2(f3[r], i3[r]);
                }
            }
            __syncthreads();

            if (isUpd) {
                float df = 0.f, di = 0.f;
                #pragma unroll
                for (int ch = 0; ch < 16; ++ch) {
                    const float2 v = part2[(ch * 128 + uc) * PSTB + ur];
                    df += v.x;
                    di += v.y;
                }
                float Cn = sgc * sigf(gi + di) + Creg * sigf(gf + df);
                Cn = (cl > 0) ? Cn : 0.0f;
                Creg = Cn;
                const uint32_t vb = pkbf(Cn, Cn);
                cstu(nxtT + (r0 + ur) * HD + h0 + uc,
                     (vb << 16) | ((uint32_t)(t + 1) & 0xFFFFu));
            }
        }

        __syncthreads();
        {
            const int rr = tid >> 8, wi = tid & 255;
            const uint32_t w = CbS[rr * CBW + wi];
            Cs[rr * CPAD + cpi(2 * wi)]     = __uint_as_float((w & 0xFFFFu) << 16);
            Cs[rr * CPAD + cpi(2 * wi + 1)] = __uint_as_float(w & 0xFFFF0000u);
            __syncthreads();

            const int oc = tid & 127, och = tid >> 7;
            float ao0 = 0.f, ao1 = 0.f;
            #pragma unroll 4
            for (int k = 0; k < 128; ++k) {
                const int hp  = och * 128 + k;
                const int hpp = cpi(hp);
                const float wo = ldv<true>(Woc, hp * HD + h0 + oc);
                ao0 += wo * Cs[0 * CPAD + hpp];
                ao1 += wo * Cs[1 * CPAD + hpp];
            }
            part2[(och * 128 + oc) * PSTB] = make_float2(ao0, ao1);
            __syncthreads();
            if (isUpd) {
                float s = 0.f;
                #pragma unroll
                for (int ch = 0; ch < 4; ++ch) {
                    const float2 v = part2[(ch * 128 + uc) * PSTB];
                    s += ur ? v.y : v.x;
                }
                const int cl2 = idx[ur * TT + TT - 1];
                const float o = sigf(G[cl2 * 2048 + 1024 + h0 + uc] + s);
                cst(&Hfb[(r0 + ur) * HD + h0 + uc], tanhf(Creg) * o);
            }
        }

        // ---- FUSED projection (bf16 out), rank 0 of each 4-WG group ----
        gbarrier(bar, &bi, GWGB);
        if (rank == 0) {
            float* hv = (float*)part2;    // [2][512] staged h
            hv[0 * 512 + tid] = cld(Hfb + (r0 + 0) * HD + tid);
            hv[1 * 512 + tid] = cld(Hfb + (r0 + 1) * HD + tid);
            __syncthreads();
            const int row = tid >> 8, c = tid & 255;   // 2 x 256
            float p = -1e30f;
            if (c < NCLS) {
                p = ldv<true>(bp, c);
                const float* hr = hv + row * 512;
                for (int h = 0; h < HD; ++h)
                    p += hr[h] * ldv<true>(Wph, h * NCLS + c);
            }
            float* ps = hv + 2 * 512;     // [2][256] logits
            ps[row * 256 + c] = p;
            __syncthreads();
            if (c == 0) {
                const float* pr = ps + row * 256;
                float m = -1e30f;
                for (int n = 0; n < NCLS; ++n) m = fmaxf(m, pr[n]);
                float sum = 0.0f;
                for (int n = 0; n < NCLS; ++n) sum += expf(pr[n] - m);
                lseS[row] = m + logf(sum);
            }
            __syncthreads();
            if (c < NCLS)
                ((bf16*)out)[(r0 + row) * NCLS + c] =
                    __float2bfloat16(ps[row * 256 + c] - lseS[row]);
        }
    }
}

// ---------------------------------------------------------------------------
extern "C" void kernel_launch(void* const* d_in, const int* in_sizes, int n_in,
                              void* d_out, int out_size, void* d_ws, size_t ws_size,
                              hipStream_t stream) {
    const int*  x   = (const int*)d_in[0];
    const void* emb = d_in[1];
    const void* Wfx = d_in[2];
    const void* Wfc = d_in[3];
    const void* bfv = d_in[4];
    const void* Wix = d_in[5];
    const void* Wic = d_in[6];
    const void* biv = d_in[7];
    const void* Wox = d_in[8];
    const void* Woc = d_in[9];
    const void* bov = d_in[10];
    const void* Wcx = d_in[11];
    const void* bcv = d_in[12];
    const void* Wph = d_in[13];
    const void* bp  = d_in[14];

    unsigned* bars = (unsigned*)((char*)d_ws + WS_BAR);
    float*    G    = (float*)((char*)d_ws + WS_G);
    float*    C0   = (float*)((char*)d_ws + WS_C0);
    float*    C1   = (float*)((char*)d_ws + WS_C1);
    float*    Hfb  = (float*)((char*)d_ws + WS_HFB);

    // Dispatch 1: G build (runtime dtype) + bars zeroing for this launch.
    build_G_k<<<dim3(NEMB, 8), 256, 0, stream>>>(emb, Wfx, Wix, Wox, Wcx,
                                                 bfv, biv, bov, bcv, G, bars);

    // Dispatch 2: fused recurrence + projection (cooperative).
    {
        void* args[] = {(void*)&x, (void*)&G,
                        (void*)&Wfc, (void*)&Wic, (void*)&Woc,
                        (void*)&C0, (void*)&C1, (void*)&Hfb, (void*)&bars,
                        (void*)&emb, (void*)&Wph, (void*)&bp, (void*)&d_out};
        hipLaunchCooperativeKernel((const void*)recur_fused, dim3(256), dim3(THR),
                                   args, 0, stream);
    }
}

// Round 17
// 1432.005 us; speedup vs baseline: 1.0960x; 1.0757x over previous
//
#include <hip/hip_runtime.h>
#include <hip/hip_bf16.h>
#include <stdint.h>

#define HD   512   // hidden dim H
#define ID   128   // input dim I
#define NCLS 100   // num classes
#define TT   512   // sequence length T
#define BB   128   // batch B
#define NEMB 101   // NC + 1 embedding rows
#define THR  512   // threads per recurrence WG (8 waves, 2 waves/SIMD)

// f32 geometry: 32 groups x 8 WGs x 64 cols, 4 rows/group.
#define NGRPF 32
#define GWGF  8
#define RPGF  4
#define COLSF 64
// bf16 geometry: 64 groups x 4 WGs x 128 cols, 2 rows/group.
#define NGRPB 64
#define GWGB  4
#define RPGB  2
#define COLSB 128

#define CPAD 640   // f32 LDS C row stride (32 chunks x (16 data + 4 pad))
#define CBW  260   // packed-bf16 C row stride in u32 (256 pairs + 4 pad)
#define PROW 2056  // f32 partials row stride in float2 (2048 slots + 8 pad)
#define PSTB 3     // bf16-path partials stride in float2

// workspace layout (bytes)
#define WS_FLAG 0
#define WS_BAR  4096                   // u32 bars[NGRP*32]
#define WS_G    65536                  // float G[101][2048]  (808 KB)
#define WS_C0   (1u * 1024 * 1024)     // C0: tagged u32 exchange buffer
#define WS_C1   (WS_C0 + 262144)
#define WS_HFB  (WS_C1 + 262144)       // float Hfb[128][512] (256 KB)
#define NBARU   4096
#define NCU     65536                  // u32s per C buffer

using bf16 = __hip_bfloat16;

__device__ __forceinline__ float b2f(bf16 v) { return __bfloat162float(v); }
__device__ __forceinline__ float sigf(float x) { return 1.0f / (1.0f + expf(-x)); }

// Agent-scope accessors — proven (die-level coherence point).
// LEDGER:
//  r1: separate flag+data exchange — lost to central RMW.
//  r3/r4: sc0 same-XCD L2 transport — stale L1; refuted. Do not retry.
//  r5: ext_vector v2f — hipcc scalarizes.
//  r6-r8 "nulls" VOID: flag=0 (inputs f32); bf16-path edits were dead.
//  r9: tagged dataflow (2-bit step tag in mantissa) — WIN 1469->1375.
//  r10/r11: wave-local stage, pk_fma — NULL: compute off critical chain.
//  r12: [col][4row] repack — REGRESSION: broke publish coalescing.
//  r13: single barrier/step + [row][slot] partials — WIN.
//  r14: dispatch merge — total 1420 (best), recur 1401, prologue gap 19us.
//  r15: host-side size discrimination FAILED (in_sizes not bytes); also
//      showed r13's 1334 was session variance (same source -> 1403).
//  r16: 2-dispatch fold + fused proj — recur_fused 1353 (best dispatch)
//      but total 1540: prologue gap blew to 187us (probe/bars-in-build_G
//      and/or C first-touch moved into the coop kernel; not attributable).
//  r17 (this round): RECOMBINE proven pieces — r14's prologue (init_k
//      zeroing bars+C+flag; flag-gated build_G_k; measured 19us gap) +
//      r16's fused recur_fused (1353) reading the flag from workspace
//      (one load) instead of probe_flag. 3 dispatches. Hot loop verbatim.
__device__ __forceinline__ float cld(const float* p) {
    return __hip_atomic_load(p, __ATOMIC_RELAXED, __HIP_MEMORY_SCOPE_AGENT);
}
__device__ __forceinline__ void cst(float* p, float v) {
    __hip_atomic_store(p, v, __ATOMIC_RELAXED, __HIP_MEMORY_SCOPE_AGENT);
}
__device__ __forceinline__ void cstu(uint32_t* p, uint32_t v) {
    __hip_atomic_store(p, v, __ATOMIC_RELAXED, __HIP_MEMORY_SCOPE_AGENT);
}
__device__ __forceinline__ uint32_t cldu(const uint32_t* p) {
    return __hip_atomic_load(p, __ATOMIC_RELAXED, __HIP_MEMORY_SCOPE_AGENT);
}
__device__ __forceinline__ uint64_t cldu8(const uint64_t* p) {
    return __hip_atomic_load(p, __ATOMIC_RELAXED, __HIP_MEMORY_SCOPE_AGENT);
}

// pack two f32 into bf16x2 (low = first arg) — gfx950-verified instruction
__device__ __forceinline__ uint32_t pkbf(float x, float y) {
    uint32_t u;
    asm("v_cvt_pk_bf16_f32 %0, %1, %2" : "=v"(u) : "v"(x), "v"(y));
    return u;
}
// 2-way bf16 dot with f32 accumulate (VOP3P) — schedulable.
#define DOT2(acc, w, c) \
    asm("v_dot2_f32_bf16 %0, %1, %2, %0" : "+v"(acc) : "v"(w), "v"(c))

template <bool BF>
__device__ __forceinline__ float ldv(const void* p, int i) {
    if constexpr (BF) return b2f(((const bf16*)p)[i]);
    else              return ((const float*)p)[i];
}

// padded f32 Cs index for h' (16 data floats + 4 pad per chunk)
__device__ __forceinline__ int cpi(int h) { return (h >> 4) * 20 + (h & 15); }

// ---------------------------------------------------------------------------
// Group barrier — startup/epilogue only (per-step barriers deleted since r9).
// ---------------------------------------------------------------------------
__device__ __forceinline__ void gbarrier(unsigned* cnt, unsigned* iter, int gwg) {
    __syncthreads();
    if (threadIdx.x == 0) {
        __hip_atomic_fetch_add(cnt, 1u, __ATOMIC_RELAXED, __HIP_MEMORY_SCOPE_AGENT);
        const unsigned tgt = (*iter + 1u) * (unsigned)gwg;
        while (__hip_atomic_load(cnt, __ATOMIC_RELAXED, __HIP_MEMORY_SCOPE_AGENT) < tgt)
            ;
    }
    ++*iter;
    __syncthreads();
}

// ---------------------------------------------------------------------------
// Dtype sniffer + bars + FULL C-buffer zeroing (r14-proven prologue; also
// moves exchange-buffer first-touch out of the cooperative kernel).
// emb bytes [256,512) are zero iff f32 (row 0 is exactly 0.0).
// ---------------------------------------------------------------------------
__global__ void init_k(const uint32_t* __restrict__ emb_raw,
                       int* __restrict__ flag, unsigned* __restrict__ bars,
                       uint32_t* __restrict__ c0, uint32_t* __restrict__ c1) {
    const int t = blockIdx.x * 1024 + threadIdx.x;
    for (int k = t; k < NBARU; k += 8192) bars[k] = 0u;
    for (int k = t; k < NCU; k += 8192) { c0[k] = 0u; c1[k] = 0u; }
    if (t == 0) {
        uint32_t acc = 0;
        for (int i = 64; i < 128; ++i) acc |= emb_raw[i];
        *flag = (acc == 0u) ? 0 : 1;
    }
}

// ---------------------------------------------------------------------------
// G[c][j]: input-side gate pre-activations per class. j = q*512 + col,
// q in {0:f, 1:i, 2:o, 3:ctilde}; ctilde quarter pre-sigmoided.
// Merged runtime-dtype kernel (r14-proven; flag from workspace).
// ---------------------------------------------------------------------------
template <bool BF>
__device__ __forceinline__ void build_G_body(
    const void* emb, const void* Wfx, const void* Wix,
    const void* Wox, const void* Wcx,
    const void* bfv, const void* biv, const void* bov, const void* bcv,
    float* G) {
    const int c   = blockIdx.x;
    const int j   = blockIdx.y * 256 + threadIdx.x;
    const int q   = j >> 9;
    const int col = j & 511;
    const void* W  = (q == 0) ? Wfx : (q == 1) ? Wix : (q == 2) ? Wox : Wcx;
    const void* bv = (q == 0) ? bfv : (q == 1) ? biv : (q == 2) ? bov : bcv;
    float acc = ldv<BF>(bv, col);
    #pragma unroll 4
    for (int i = 0; i < ID; ++i)
        acc += ldv<BF>(emb, c * ID + i) * ldv<BF>(W, i * HD + col);
    if (q == 3) acc = sigf(acc);
    G[c * 2048 + j] = acc;
}

__global__ void build_G_k(const int* __restrict__ flag,
                          const void* __restrict__ emb,
                          const void* __restrict__ Wfx, const void* __restrict__ Wix,
                          const void* __restrict__ Wox, const void* __restrict__ Wcx,
                          const void* __restrict__ bfv, const void* __restrict__ biv,
                          const void* __restrict__ bov, const void* __restrict__ bcv,
                          float* __restrict__ G) {
    if (*flag == 0) build_G_body<false>(emb, Wfx, Wix, Wox, Wcx, bfv, biv, bov, bcv, G);
    else            build_G_body<true >(emb, Wfx, Wix, Wox, Wcx, bfv, biv, bov, bcv, G);
}

// ---------------------------------------------------------------------------
// FUSED recurrence + projection (single cooperative dispatch; r16-proven,
// flag now a single workspace load). f32 hot loop = r13 verbatim: tagged
// dataflow (2-bit step tag), wave-local narrow-poll stage, scalar f32 dot,
// single barrier/step with double-buffered [row][slot] partials. Epilogue:
// o-gate -> Hfb via cst -> group gbarrier -> rank0 projects its rows ->
// log_softmax -> out.
// ---------------------------------------------------------------------------
__global__ __launch_bounds__(THR, 2) void recur_fused(
    const int* __restrict__ flag,
    const int* __restrict__ x, const float* __restrict__ G,
    const void* __restrict__ Wfc, const void* __restrict__ Wic,
    const void* __restrict__ Woc,
    float* __restrict__ C0, float* __restrict__ C1,
    float* __restrict__ Hfb, unsigned* __restrict__ bars,
    const void* __restrict__ Wph, const void* __restrict__ bp,
    void* __restrict__ out)
{
    __shared__ __align__(16) float Cs[RPGF * CPAD];       // 10.2 KB
    __shared__ __align__(16) uint32_t CbS[RPGB * CBW];    // 2.1 KB (bf16 path)
    __shared__ __align__(8)  float2 part2[2 * RPGF * PROW]; // 128.5 KB
    __shared__ int idx[RPGF * TT];                        // 8 KB
    __shared__ int lz[RPGF];
    __shared__ float lseS[RPGF];

    const int blk = blockIdx.x;
    const int tid = threadIdx.x;
    unsigned bi = 0;
    const int fl = *flag;

    if (fl == 0) {
        // ===== f32 path (LIVE): wave-local tagged dataflow (r13) ==========
        const int grp   = blk >> 3;       // 0..31
        const int rank  = blk & 7;        // 0..7
        const int r0    = grp * RPGF;
        const int h0    = rank * COLSF;
        const int cp    = tid & 15;       // cols cp, +16, +32, +48
        const int chunk = tid >> 4;       // 0..31 (16 h' each)
        unsigned* bar = bars + grp * 32;

        // ---- stage x rows (2048 ints), find group start ----
        idx[tid]        = x[r0 * TT + tid];
        idx[tid + 512]  = x[r0 * TT + tid + 512];
        idx[tid + 1024] = x[r0 * TT + tid + 1024];
        idx[tid + 1536] = x[r0 * TT + tid + 1536];
        for (int k = tid; k < RPGF * CPAD; k += THR) Cs[k] = 0.0f;  // t0==TT edge
        if (tid < RPGF) lz[tid] = -1;
        __syncthreads();
        #pragma unroll
        for (int r = 0; r < RPGF; ++r)
            if (idx[r * TT + tid] == 0) atomicMax(&lz[r], tid);
        __syncthreads();
        int t0 = TT;
        #pragma unroll
        for (int r = 0; r < RPGF; ++r) t0 = min(t0, lz[r] + 1);
        // t0 is group-uniform.

        // ---- 128 pinned f32 weights: 4 cols x 2 gates x 16 h' ----
        float wf0[16], wf1[16], wf2[16], wf3[16];
        float wi0[16], wi1[16], wi2[16], wi3[16];
        #pragma unroll
        for (int k = 0; k < 16; ++k) {
            const int hp = chunk * 16 + k;
            wf0[k] = ldv<false>(Wfc, hp * HD + h0 + cp);
            wf1[k] = ldv<false>(Wfc, hp * HD + h0 + cp + 16);
            wf2[k] = ldv<false>(Wfc, hp * HD + h0 + cp + 32);
            wf3[k] = ldv<false>(Wfc, hp * HD + h0 + cp + 48);
            wi0[k] = ldv<false>(Wic, hp * HD + h0 + cp);
            wi1[k] = ldv<false>(Wic, hp * HD + h0 + cp + 16);
            wi2[k] = ldv<false>(Wic, hp * HD + h0 + cp + 32);
            wi3[k] = ldv<false>(Wic, hp * HD + h0 + cp + 48);
        }
        #pragma unroll
        for (int k = 0; k < 16; ++k)
            asm volatile("" : "+v"(wf0[k]), "+v"(wf1[k]), "+v"(wf2[k]), "+v"(wf3[k]),
                              "+v"(wi0[k]), "+v"(wi1[k]), "+v"(wi2[k]), "+v"(wi3[k]));

        const bool isUpd = (tid < COLSF * RPGF);
        const int uc = tid & 63, ur = tid >> 6;
        const int pe = cpi(tid);

        // ---- owner-init step tags (values 0). Active buf: tag t0; other
        // buf: stale marker (t0+3)&3 (can't alias the first publish). ----
        {
            uint32_t* tA = (uint32_t*)((t0 & 1) ? C1 : C0);
            uint32_t* tB = (uint32_t*)((t0 & 1) ? C0 : C1);
            if (isUpd) {
                cstu(tA + (r0 + ur) * HD + h0 + uc, (uint32_t)(t0 & 3));
                cstu(tB + (r0 + ur) * HD + h0 + uc, (uint32_t)((t0 + 3) & 3));
            }
        }
        gbarrier(bar, &bi, GWGF);         // startup: inits visible

        float Creg = 0.0f;
        for (int t = t0; t < TT; ++t) {
            // re-pin weights every iteration (r7/r8/r10 lesson)
            #pragma unroll
            for (int k = 0; k < 16; ++k)
                asm volatile("" : "+v"(wf0[k]), "+v"(wf1[k]), "+v"(wf2[k]), "+v"(wf3[k]),
                                  "+v"(wi0[k]), "+v"(wi1[k]), "+v"(wi2[k]), "+v"(wi3[k]));

            const uint32_t* curT = (const uint32_t*)((t & 1) ? C1 : C0);
            uint32_t*       nxtT = (uint32_t*)((t & 1) ? C0 : C1);

            // ---- prefetch G gate operands (in flight during the spin) ----
            float gf = 0.f, gi = 0.f, sgc = 0.f;
            int cl = 1;
            if (isUpd) {
                cl = idx[ur * TT + t];
                const float* Gr = G + cl * 2048;
                gf  = Gr[h0 + uc];
                gi  = Gr[512 + h0 + uc];
                sgc = Gr[1536 + h0 + uc];
            }

            // ---- WAVE-LOCAL stage: wave w spins only on rank-block w ----
            {
                const uint32_t* s0 = curT + (r0 + 0) * HD + tid;
                const uint32_t* s1 = curT + (r0 + 1) * HD + tid;
                const uint32_t* s2 = curT + (r0 + 2) * HD + tid;
                const uint32_t* s3 = curT + (r0 + 3) * HD + tid;
                const uint32_t exp = (uint32_t)t & 3u;
                uint32_t w0, w1, w2, w3;
                do { w0 = cldu(s0); } while ((w0 ^ exp) & 3u);
                for (;;) {
                    w1 = cldu(s1); w2 = cldu(s2); w3 = cldu(s3);
                    if ((((w1 ^ exp) | (w2 ^ exp) | (w3 ^ exp)) & 3u) == 0u)
                        break;
                }
                Cs[0 * CPAD + pe] = __uint_as_float(w0 & ~3u);
                Cs[1 * CPAD + pe] = __uint_as_float(w1 & ~3u);
                Cs[2 * CPAD + pe] = __uint_as_float(w2 & ~3u);
                Cs[3 * CPAD + pe] = __uint_as_float(w3 & ~3u);
            }
            // per-wave fence: same-wave DS ops complete in order.
            asm volatile("s_waitcnt lgkmcnt(0)" ::: "memory");

            // ---- dot over own block (scalar f32, r10-proven) ----
            float f0[RPGF], f1[RPGF], f2[RPGF], f3[RPGF];
            float i0[RPGF], i1[RPGF], i2[RPGF], i3[RPGF];
            #pragma unroll
            for (int r = 0; r < RPGF; ++r) {
                f0[r] = 0.f; f1[r] = 0.f; f2[r] = 0.f; f3[r] = 0.f;
                i0[r] = 0.f; i1[r] = 0.f; i2[r] = 0.f; i3[r] = 0.f;
            }
            {
                const int cb = chunk * 5;
                #pragma unroll
                for (int j = 0; j < 4; ++j) {
                    #pragma unroll
                    for (int r = 0; r < RPGF; ++r) {
                        const float4 cv = reinterpret_cast<const float4*>(
                            Cs + r * CPAD)[cb + j];
                        f0[r] += wf0[4*j]*cv.x + wf0[4*j+1]*cv.y + wf0[4*j+2]*cv.z + wf0[4*j+3]*cv.w;
                        f1[r] += wf1[4*j]*cv.x + wf1[4*j+1]*cv.y + wf1[4*j+2]*cv.z + wf1[4*j+3]*cv.w;
                        f2[r] += wf2[4*j]*cv.x + wf2[4*j+1]*cv.y + wf2[4*j+2]*cv.z + wf2[4*j+3]*cv.w;
                        f3[r] += wf3[4*j]*cv.x + wf3[4*j+1]*cv.y + wf3[4*j+2]*cv.z + wf3[4*j+3]*cv.w;
                        i0[r] += wi0[4*j]*cv.x + wi0[4*j+1]*cv.y + wi0[4*j+2]*cv.z + wi0[4*j+3]*cv.w;
                        i1[r] += wi1[4*j]*cv.x + wi1[4*j+1]*cv.y + wi1[4*j+2]*cv.z + wi1[4*j+3]*cv.w;
                        i2[r] += wi2[4*j]*cv.x + wi2[4*j+1]*cv.y + wi2[4*j+2]*cv.z + wi2[4*j+3]*cv.w;
                        i3[r] += wi3[4*j]*cv.x + wi3[4*j+1]*cv.y + wi3[4*j+2]*cv.z + wi3[4*j+3]*cv.w;
                    }
                }
            }

            // ---- write partials: buf[t&1], [row][slot] (conflict-free) ----
            {
                float2* Pb = part2 + (t & 1) * (RPGF * PROW);
                #pragma unroll
                for (int r = 0; r < RPGF; ++r) {
                    float2* Pr = Pb + r * PROW + chunk * 64;
                    Pr[cp]      = make_float2(f0[r], i0[r]);
                    Pr[cp + 16] = make_float2(f1[r], i1[r]);
                    Pr[cp + 32] = make_float2(f2[r], i2[r]);
                    Pr[cp + 48] = make_float2(f3[r], i3[r]);
                }
            }
            __syncthreads();              // SINGLE barrier: partials ready

            // ---- update + tagged publish ----
            if (isUpd) {
                const float2* Pr = part2 + (t & 1) * (RPGF * PROW) + ur * PROW;
                float df = 0.f, di = 0.f;
                #pragma unroll
                for (int ch = 0; ch < 32; ++ch) {
                    const float2 v = Pr[ch * 64 + uc];
                    df += v.x;
                    di += v.y;
                }
                float Cn = sgc * sigf(gi + di) + Creg * sigf(gf + df);
                Cn = (cl > 0) ? Cn : 0.0f;
                Creg = Cn;
                cstu(nxtT + (r0 + ur) * HD + h0 + uc,
                     (__float_as_uint(Cn) & ~3u) | ((uint32_t)(t + 1) & 3u));
            }
            // no barrier, no drain: consumers spin on the in-word tag.
        }

        // ---- o-gate + h. Cs holds the carry entering step T-1. ----
        __syncthreads();                  // last update's part2 reads done
        {
            const int oc = tid & 63, och = tid >> 6;
            float ao[RPGF];
            #pragma unroll
            for (int r = 0; r < RPGF; ++r) ao[r] = 0.0f;
            #pragma unroll 4
            for (int k = 0; k < 64; ++k) {
                const int hp = och * 64 + k;
                const int hpp = cpi(hp);
                const float wo = ldv<false>(Woc, hp * HD + h0 + oc);
                #pragma unroll
                for (int r = 0; r < RPGF; ++r)
                    ao[r] += wo * Cs[r * CPAD + hpp];
            }
            {
                #pragma unroll
                for (int r2 = 0; r2 < RPGF / 2; ++r2)
                    part2[r2 * PROW + och * 64 + oc] =
                        make_float2(ao[2 * r2], ao[2 * r2 + 1]);
            }
            __syncthreads();
            if (isUpd) {
                const float2* Pr = part2 + (ur >> 1) * PROW;
                float s = 0.f;
                #pragma unroll
                for (int ch = 0; ch < 8; ++ch) {
                    const float2 v = Pr[ch * 64 + uc];
                    s += (ur & 1) ? v.y : v.x;
                }
                const int cl2 = idx[ur * TT + TT - 1];
                const float o = sigf(G[cl2 * 2048 + 1024 + h0 + uc] + s);
                cst(&Hfb[(r0 + ur) * HD + h0 + uc], tanhf(Creg) * o);
            }
        }

        // ---- FUSED projection: rank 0 projects its 4 rows after the
        // group barrier (Hfb stores drained + agent-visible). ----
        gbarrier(bar, &bi, GWGF);
        if (rank == 0) {
            float* hv = (float*)part2;    // [4][512] staged h
            hv[0 * 512 + tid] = cld(Hfb + (r0 + 0) * HD + tid);
            hv[1 * 512 + tid] = cld(Hfb + (r0 + 1) * HD + tid);
            hv[2 * 512 + tid] = cld(Hfb + (r0 + 2) * HD + tid);
            hv[3 * 512 + tid] = cld(Hfb + (r0 + 3) * HD + tid);
            __syncthreads();
            const int row = tid >> 7, c = tid & 127;   // 4 x 128
            float p = -1e30f;
            if (c < NCLS) {
                p = ldv<false>(bp, c);
                const float* hr = hv + row * 512;
                for (int h = 0; h < HD; ++h)
                    p += hr[h] * ldv<false>(Wph, h * NCLS + c);
            }
            float* ps = hv + 4 * 512;     // [4][128] logits
            ps[row * 128 + c] = p;
            __syncthreads();
            if (c == 0) {
                const float* pr = ps + row * 128;
                float m = -1e30f;
                for (int n = 0; n < NCLS; ++n) m = fmaxf(m, pr[n]);
                float sum = 0.0f;
                for (int n = 0; n < NCLS; ++n) sum += expf(pr[n] - m);
                lseS[row] = m + logf(sum);
            }
            __syncthreads();
            if (c < NCLS)
                ((float*)out)[(r0 + row) * NCLS + c] = ps[row * 128 + c] - lseS[row];
        }
    } else {
        // ===== bf16 path: r8 tagged dataflow + fused proj =================
        const int grp   = blk >> 2;       // 0..63
        const int rank  = blk & 3;        // 0..3
        const int r0    = grp * RPGB;
        const int h0    = rank * COLSB;
        const int cp    = tid & 31;
        const int chunk = tid >> 5;
        unsigned* bar = bars + grp * 32;

        idx[tid]       = x[r0 * TT + tid];
        idx[tid + 512] = x[r0 * TT + tid + 512];
        for (int k = tid; k < RPGB * CBW; k += THR) CbS[k] = 0u;
        if (tid < RPGB) lz[tid] = -1;
        __syncthreads();
        #pragma unroll
        for (int r = 0; r < RPGB; ++r)
            if (idx[r * TT + tid] == 0) atomicMax(&lz[r], tid);
        __syncthreads();
        int t0 = TT;
        #pragma unroll
        for (int r = 0; r < RPGB; ++r) t0 = min(t0, lz[r] + 1);

        const uint16_t* Wfr = (const uint16_t*)Wfc;
        const uint16_t* Wir = (const uint16_t*)Wic;
        uint32_t wf0[16], wf1[16], wf2[16], wf3[16];
        uint32_t wi0[16], wi1[16], wi2[16], wi3[16];
        #pragma unroll
        for (int p = 0; p < 16; ++p) {
            const int hp = chunk * 32 + 2 * p;
            const int b0 = hp * HD + h0 + cp, b1 = (hp + 1) * HD + h0 + cp;
            wf0[p] = (uint32_t)Wfr[b0]      | ((uint32_t)Wfr[b1]      << 16);
            wf1[p] = (uint32_t)Wfr[b0 + 32] | ((uint32_t)Wfr[b1 + 32] << 16);
            wf2[p] = (uint32_t)Wfr[b0 + 64] | ((uint32_t)Wfr[b1 + 64] << 16);
            wf3[p] = (uint32_t)Wfr[b0 + 96] | ((uint32_t)Wfr[b1 + 96] << 16);
            wi0[p] = (uint32_t)Wir[b0]      | ((uint32_t)Wir[b1]      << 16);
            wi1[p] = (uint32_t)Wir[b0 + 32] | ((uint32_t)Wir[b1 + 32] << 16);
            wi2[p] = (uint32_t)Wir[b0 + 64] | ((uint32_t)Wir[b1 + 64] << 16);
            wi3[p] = (uint32_t)Wir[b0 + 96] | ((uint32_t)Wir[b1 + 96] << 16);
        }
        #pragma unroll
        for (int p = 0; p < 16; ++p)
            asm volatile("" : "+v"(wf0[p]), "+v"(wf1[p]), "+v"(wf2[p]), "+v"(wf3[p]),
                              "+v"(wi0[p]), "+v"(wi1[p]), "+v"(wi2[p]), "+v"(wi3[p]));

        const bool isUpd = (tid < COLSB * RPGB);
        const int uc = tid & 127, ur = tid >> 7;

        if (isUpd && t0 > 0) {
            uint32_t* b0 = (uint32_t*)((t0 & 1) ? C1 : C0);
            cstu(b0 + (r0 + ur) * HD + h0 + uc, (uint32_t)t0 & 0xFFFFu);
        }
        gbarrier(bar, &bi, GWGB);

        float Creg = 0.0f;
        const int srow = tid >> 8;
        const int spr  = tid & 255;

        for (int t = t0; t < TT; ++t) {
            #pragma unroll
            for (int p = 0; p < 16; ++p)
                asm volatile("" : "+v"(wf0[p]), "+v"(wf1[p]), "+v"(wf2[p]), "+v"(wf3[p]),
                                  "+v"(wi0[p]), "+v"(wi1[p]), "+v"(wi2[p]), "+v"(wi3[p]));

            const uint32_t* curT = (const uint32_t*)((t & 1) ? C1 : C0);
            uint32_t*       nxtT = (uint32_t*)((t & 1) ? C0 : C1);

            float gf = 0.f, gi = 0.f, sgc = 0.f;
            int cl = 1;
            if (isUpd) {
                cl = idx[ur * TT + t];
                const float* Gr = G + cl * 2048;
                gf  = Gr[h0 + uc];
                gi  = Gr[512 + h0 + uc];
                sgc = Gr[1536 + h0 + uc];
            }

            {
                const uint64_t* src = (const uint64_t*)(
                    curT + (r0 + srow) * HD + 2 * spr);
                const uint32_t exp = (uint32_t)t & 0xFFFFu;
                uint32_t w0, w1;
                for (;;) {
                    const uint64_t d = cldu8(src);
                    w0 = (uint32_t)d;
                    w1 = (uint32_t)(d >> 32);
                    if ((((w0 ^ exp) | (w1 ^ exp)) & 0xFFFFu) == 0u) break;
                }
                CbS[srow * CBW + spr] = (w0 >> 16) | (w1 & 0xFFFF0000u);
            }
            __syncthreads();

            float f0[RPGB], f1[RPGB], f2[RPGB], f3[RPGB];
            float i0[RPGB], i1[RPGB], i2[RPGB], i3[RPGB];
            #pragma unroll
            for (int r = 0; r < RPGB; ++r) {
                f0[r] = 0.f; f1[r] = 0.f; f2[r] = 0.f; f3[r] = 0.f;
                i0[r] = 0.f; i1[r] = 0.f; i2[r] = 0.f; i3[r] = 0.f;
            }
            {
                const int cb = chunk * 16;
                #pragma unroll
                for (int hh = 0; hh < 4; ++hh) {
                    #pragma unroll
                    for (int r = 0; r < RPGB; ++r) {
                        const uint4 cv = *reinterpret_cast<const uint4*>(
                            CbS + r * CBW + cb + 4 * hh);
                        const int p = 4 * hh;
                        DOT2(f0[r], wf0[p + 0], cv.x); DOT2(f0[r], wf0[p + 1], cv.y);
                        DOT2(f0[r], wf0[p + 2], cv.z); DOT2(f0[r], wf0[p + 3], cv.w);
                        DOT2(f1[r], wf1[p + 0], cv.x); DOT2(f1[r], wf1[p + 1], cv.y);
                        DOT2(f1[r], wf1[p + 2], cv.z); DOT2(f1[r], wf1[p + 3], cv.w);
                        DOT2(f2[r], wf2[p + 0], cv.x); DOT2(f2[r], wf2[p + 1], cv.y);
                        DOT2(f2[r], wf2[p + 2], cv.z); DOT2(f2[r], wf2[p + 3], cv.w);
                        DOT2(f3[r], wf3[p + 0], cv.x); DOT2(f3[r], wf3[p + 1], cv.y);
                        DOT2(f3[r], wf3[p + 2], cv.z); DOT2(f3[r], wf3[p + 3], cv.w);
                        DOT2(i0[r], wi0[p + 0], cv.x); DOT2(i0[r], wi0[p + 1], cv.y);
                        DOT2(i0[r], wi0[p + 2], cv.z); DOT2(i0[r], wi0[p + 3], cv.w);
                        DOT2(i1[r], wi1[p + 0], cv.x); DOT2(i1[r], wi1[p + 1], cv.y);
                        DOT2(i1[r], wi1[p + 2], cv.z); DOT2(i1[r], wi1[p + 3], cv.w);
                        DOT2(i2[r], wi2[p + 0], cv.x); DOT2(i2[r], wi2[p + 1], cv.y);
                        DOT2(i2[r], wi2[p + 2], cv.z); DOT2(i2[r], wi2[p + 3], cv.w);
                        DOT2(i3[r], wi3[p + 0], cv.x); DOT2(i3[r], wi3[p + 1], cv.y);
                        DOT2(i3[r], wi3[p + 2], cv.z); DOT2(i3[r], wi3[p + 3], cv.w);
                    }
                }
            }
            {
                float2* part2b = (float2*)part2;
                float2* p0 = part2b + (chunk * 128 + cp)      * PSTB;
                float2* p1 = part2b + (chunk * 128 + cp + 32) * PSTB;
                float2* p2 = part2b + (chunk * 128 + cp + 64) * PSTB;
                float2* p3 = part2b + (chunk * 128 + cp + 96) * PSTB;
                #pragma unroll
                for (int r = 0; r < RPGB; ++r) {
                    p0[r] = make_float2(f0[r], i0[r]);
                    p1[r] = make_float2(f1[r], i1[r]);
                    p2[r] = make_float2(f2[r], i2[r]);
                    p3[r] = make_float2(f3[r], i3[r]);
                }
            }
            __syncthreads();

            if (isUpd) {
                float df = 0.f, di = 0.f;
                #pragma unroll
                for (int ch = 0; ch < 16; ++ch) {
                    const float2 v = part2[(ch * 128 + uc) * PSTB + ur];
                    df += v.x;
                    di += v.y;
                }
                float Cn = sgc * sigf(gi + di) + Creg * sigf(gf + df);
                Cn = (cl > 0) ? Cn : 0.0f;
                Creg = Cn;
                const uint32_t vb = pkbf(Cn, Cn);
                cstu(nxtT + (r0 + ur) * HD + h0 + uc,
                     (vb << 16) | ((uint32_t)(t + 1) & 0xFFFFu));
            }
        }

        __syncthreads();
        {
            const int rr = tid >> 8, wi = tid & 255;
            const uint32_t w = CbS[rr * CBW + wi];
            Cs[rr * CPAD + cpi(2 * wi)]     = __uint_as_float((w & 0xFFFFu) << 16);
            Cs[rr * CPAD + cpi(2 * wi + 1)] = __uint_as_float(w & 0xFFFF0000u);
            __syncthreads();

            const int oc = tid & 127, och = tid >> 7;
            float ao0 = 0.f, ao1 = 0.f;
            #pragma unroll 4
            for (int k = 0; k < 128; ++k) {
                const int hp  = och * 128 + k;
                const int hpp = cpi(hp);
                const float wo = ldv<true>(Woc, hp * HD + h0 + oc);
                ao0 += wo * Cs[0 * CPAD + hpp];
                ao1 += wo * Cs[1 * CPAD + hpp];
            }
            part2[(och * 128 + oc) * PSTB] = make_float2(ao0, ao1);
            __syncthreads();
            if (isUpd) {
                float s = 0.f;
                #pragma unroll
                for (int ch = 0; ch < 4; ++ch) {
                    const float2 v = part2[(ch * 128 + uc) * PSTB];
                    s += ur ? v.y : v.x;
                }
                const int cl2 = idx[ur * TT + TT - 1];
                const float o = sigf(G[cl2 * 2048 + 1024 + h0 + uc] + s);
                cst(&Hfb[(r0 + ur) * HD + h0 + uc], tanhf(Creg) * o);
            }
        }

        // ---- FUSED projection (bf16 out), rank 0 of each 4-WG group ----
        gbarrier(bar, &bi, GWGB);
        if (rank == 0) {
            float* hv = (float*)part2;    // [2][512] staged h
            hv[0 * 512 + tid] = cld(Hfb + (r0 + 0) * HD + tid);
            hv[1 * 512 + tid] = cld(Hfb + (r0 + 1) * HD + tid);
            __syncthreads();
            const int row = tid >> 8, c = tid & 255;   // 2 x 256
            float p = -1e30f;
            if (c < NCLS) {
                p = ldv<true>(bp, c);
                const float* hr = hv + row * 512;
                for (int h = 0; h < HD; ++h)
                    p += hr[h] * ldv<true>(Wph, h * NCLS + c);
            }
            float* ps = hv + 2 * 512;     // [2][256] logits
            ps[row * 256 + c] = p;
            __syncthreads();
            if (c == 0) {
                const float* pr = ps + row * 256;
                float m = -1e30f;
                for (int n = 0; n < NCLS; ++n) m = fmaxf(m, pr[n]);
                float sum = 0.0f;
                for (int n = 0; n < NCLS; ++n) sum += expf(pr[n] - m);
                lseS[row] = m + logf(sum);
            }
            __syncthreads();
            if (c < NCLS)
                ((bf16*)out)[(r0 + row) * NCLS + c] =
                    __float2bfloat16(ps[row * 256 + c] - lseS[row]);
        }
    }
}

// ---------------------------------------------------------------------------
extern "C" void kernel_launch(void* const* d_in, const int* in_sizes, int n_in,
                              void* d_out, int out_size, void* d_ws, size_t ws_size,
                              hipStream_t stream) {
    const int*  x   = (const int*)d_in[0];
    const void* emb = d_in[1];
    const void* Wfx = d_in[2];
    const void* Wfc = d_in[3];
    const void* bfv = d_in[4];
    const void* Wix = d_in[5];
    const void* Wic = d_in[6];
    const void* biv = d_in[7];
    const void* Wox = d_in[8];
    const void* Woc = d_in[9];
    const void* bov = d_in[10];
    const void* Wcx = d_in[11];
    const void* bcv = d_in[12];
    const void* Wph = d_in[13];
    const void* bp  = d_in[14];

    int*      flag = (int*)((char*)d_ws + WS_FLAG);
    unsigned* bars = (unsigned*)((char*)d_ws + WS_BAR);
    float*    G    = (float*)((char*)d_ws + WS_G);
    float*    C0   = (float*)((char*)d_ws + WS_C0);
    float*    C1   = (float*)((char*)d_ws + WS_C1);
    float*    Hfb  = (float*)((char*)d_ws + WS_HFB);

    // Dispatch 1: flag sniff + bars + C-buffer zeroing (r14-proven prologue).
    init_k<<<8, 1024, 0, stream>>>((const uint32_t*)emb, flag, bars,
                                   (uint32_t*)C0, (uint32_t*)C1);

    // Dispatch 2: G build (runtime dtype via flag).
    build_G_k<<<dim3(NEMB, 8), 256, 0, stream>>>(flag, emb, Wfx, Wix, Wox, Wcx,
                                                 bfv, biv, bov, bcv, G);

    // Dispatch 3: fused recurrence + projection (cooperative).
    {
        void* args[] = {(void*)&flag, (void*)&x, (void*)&G,
                        (void*)&Wfc, (void*)&Wic, (void*)&Woc,
                        (void*)&C0, (void*)&C1, (void*)&Hfb, (void*)&bars,
                        (void*)&Wph, (void*)&bp, (void*)&d_out};
        hipLaunchCooperativeKernel((const void*)recur_fused, dim3(256), dim3(THR),
                                   args, 0, stream);
    }
}